// Round 10
// baseline (3991.661 us; speedup 1.0000x reference)
//
#include <hip/hip_runtime.h>
#include <hip/hip_fp16.h>

// B=32, T=128, Din=H=C=1024, S=128.
// R10: persistent cooperative kernel, two independent 128-block half-grids,
// TWO barriers per step (was 3):
//  - barrier 2 (scores->softmax) replaced by owner-block alpha + per-batch
//    flag handoff: 16 owner blocks/half each compute all 128 scores + softmax
//    for one batch right after bar1 (kpre L2-resident), write alpha coherent,
//    vmcnt(0), set padded flag (gen=t+1). Consumers overlap h-proj MFMA with
//    owner score latency, then poll 16 flags and read alpha.
//  - keep: flat-release padded barrier, split arrive/wait with staging in the
//    bar-end window, MFMA pregemm, agent-scope coherent data access.
//
// MFMA 16x16x32_f16 layout (guide §3, m89-verified):
//   A: lane l, elem j -> A[l&15][(l>>4)*8+j]
//   B: lane l, elem j -> B[(l>>4)*8+j][l&15]
//   D: lane l, reg  r -> D[(l>>4)*4+r][l&15]

typedef _Float16 f16x8 __attribute__((ext_vector_type(8)));
typedef float f32x4 __attribute__((ext_vector_type(4)));
typedef unsigned long long u64;

// ---- workspace layout (bytes) ----
#define OFF_XF16  ((size_t)0)           // [32][128][1024] f16     8,388,608
#define OFF_WP    ((size_t)8388608)     // [256][96][64][8] f16   25,165,824
#define OFF_WHP   ((size_t)33554432)    // [64][32][64][8] f16     2,097,152
#define OFF_BCAT  ((size_t)35651584)    // [1024][2048] f16        4,194,304
#define OFF_KPRE  ((size_t)39845888)    // [4096][1024] f16 row-major 8,388,608
#define OFF_CWT   ((size_t)48234496)    // [32][1024][128] f16     8,388,608
#define OFF_BIASR ((size_t)56623104)    // [4096] f32                 16,384
#define OFF_H2    ((size_t)56770560)    // [2][32][1024] f16         131,072
#define OFF_ATTN  ((size_t)56901632)    // [32][1024] f16             65,536
#define OFF_SC    ((size_t)56967168)    // [32][128] f32 alpha        16,384
#define OFF_BAR   ((size_t)56983552)    // 32 KB barrier state (2 halves x 16KB)

// ---- agent-scope coherent access helpers (bypass non-coherent L2) ----
__device__ __forceinline__ u64 aload64(const void* p) {
  return __hip_atomic_load((const u64*)p, __ATOMIC_RELAXED, __HIP_MEMORY_SCOPE_AGENT);
}
__device__ __forceinline__ unsigned aload32u(const unsigned* p) {
  return __hip_atomic_load(p, __ATOMIC_RELAXED, __HIP_MEMORY_SCOPE_AGENT);
}
__device__ __forceinline__ void astore32(void* p, unsigned v) {
  __hip_atomic_store((unsigned*)p, v, __ATOMIC_RELAXED, __HIP_MEMORY_SCOPE_AGENT);
}
__device__ __forceinline__ void astore64(void* p, u64 v) {
  __hip_atomic_store((u64*)p, v, __ATOMIC_RELAXED, __HIP_MEMORY_SCOPE_AGENT);
}
__device__ __forceinline__ void astore16(void* p, unsigned short v) {
  __hip_atomic_store((unsigned short*)p, v, __ATOMIC_RELAXED, __HIP_MEMORY_SCOPE_AGENT);
}
__device__ __forceinline__ float4 aload128(const void* p) {
  float4 v;
  ((u64*)&v)[0] = aload64(p);
  ((u64*)&v)[1] = aload64((const char*)p + 8);
  return v;
}

// ---------------- one-time kernels ----------------

__global__ __launch_bounds__(256) void k_cvt_x(const float* __restrict__ x, __half* __restrict__ xf) {
  int i = blockIdx.x * 256 + threadIdx.x;
  float4 v = ((const float4*)x)[i];
  __half h4[4] = {__float2half(v.x), __float2half(v.y), __float2half(v.z), __float2half(v.w)};
  ((float2*)xf)[i] = *(float2*)h4;
}

__global__ __launch_bounds__(256) void k_build_bcat(const float* __restrict__ wq,
                                                    const float* __restrict__ wout,
                                                    __half* __restrict__ bcat) {
  int j = blockIdx.x * 256 + threadIdx.x;
  int c = blockIdx.y;
  float v = (j < 1024) ? wq[c * 1024 + j] : wout[(size_t)(j - 1024) * 2048 + c];
  bcat[c * 2048 + j] = __float2half(v);
}

// pack gate weights into MFMA A-fragment stream: wp[mt][ks][l][8]
// packed row r' = mt*16 + (l&15); original row = gate*1024 + u, r' = u*4+gate
__global__ __launch_bounds__(256) void k_pack_wp(const float* __restrict__ wih,
                                                 const float* __restrict__ whh,
                                                 __half* __restrict__ wpo) {
  int mt = blockIdx.x;
  int tid = threadIdx.x;
  int ks = blockIdx.y * 4 + (tid >> 6);
  int l = tid & 63;
  int rp = mt * 16 + (l & 15);
  int u = rp >> 2, g = rp & 3;
  int row = g * 1024 + u;
  int k = ks * 32 + (l >> 4) * 8;
  const float* src = (k < 2048) ? (wih + (size_t)row * 2048 + k)
                                : (whh + (size_t)row * 1024 + (k - 2048));
  float4 a = *(const float4*)src;
  float4 b = *(const float4*)(src + 4);
  __half o[8] = {__float2half(a.x), __float2half(a.y), __float2half(a.z), __float2half(a.w),
                 __float2half(b.x), __float2half(b.y), __float2half(b.z), __float2half(b.w)};
  *(float4*)(wpo + (((size_t)mt * 96 + ks) * 64 + l) * 8) = *(float4*)o;
}

__global__ __launch_bounds__(256) void k_pack_whp(const float* __restrict__ wout,
                                                  __half* __restrict__ wpo) {
  int nt = blockIdx.x;
  int tid = threadIdx.x;
  int ks = blockIdx.y * 4 + (tid >> 6);
  int l = tid & 63;
  int row = nt * 16 + (l & 15);
  int k = ks * 32 + (l >> 4) * 8;
  const float* src = wout + (size_t)row * 2048 + 1024 + k;
  float4 a = *(const float4*)src;
  float4 b = *(const float4*)(src + 4);
  __half o[8] = {__float2half(a.x), __float2half(a.y), __float2half(a.z), __float2half(a.w),
                 __float2half(b.x), __float2half(b.y), __float2half(b.z), __float2half(b.w)};
  *(float4*)(wpo + (((size_t)nt * 32 + ks) * 64 + l) * 8) = *(float4*)o;
}

__global__ __launch_bounds__(256) void k_bias_r(const float* __restrict__ bih,
                                                const float* __restrict__ bhh,
                                                float* __restrict__ biasr) {
  int i = blockIdx.x * 256 + threadIdx.x;
  int u = i >> 2, g = i & 3;
  biasr[i] = bih[g * 1024 + u] + bhh[g * 1024 + u];
}

// MFMA precompute GEMM: [4096 x 1024] fp32 @ [1024 x 2048] f16.
// Block = 64m x 128n, 256 thr (4 waves); wave w owns m-subtile w, 8 n-subtiles.
// n0<1024 -> kpre[m][n] row-major ; else -> cwt[b][n-1024][s], m=b*128+s.
__global__ __launch_bounds__(256) void k_pregemm(const float* __restrict__ Af,
                                                 const __half* __restrict__ Bh,
                                                 __half* __restrict__ kpre,
                                                 __half* __restrict__ cwt) {
  __shared__ __half As[64 * 40];    // [m][k], stride 40 halves
  __shared__ __half Bs[128 * 40];   // [n][k] transposed, stride 40
  int tid = threadIdx.x;
  int w = tid >> 6, l = tid & 63;
  int rl = l & 15, kg = l >> 4;
  int m0 = blockIdx.x * 64;
  int n0 = blockIdx.y * 128;
  f32x4 acc[8] = {};

  int am = tid >> 2, akq = (tid & 3) * 8;       // A staging: row, k-offset
  int bkr = tid >> 4, bnc = tid & 15;           // B staging: k-row, n-octet

  for (int k0 = 0; k0 < 1024; k0 += 32) {
    const float* ap = Af + (size_t)(m0 + am) * 1024 + k0 + akq;
    float4 a0 = *(const float4*)ap;
    float4 a1 = *(const float4*)(ap + 4);
    __half o8[8] = {__float2half(a0.x), __float2half(a0.y), __float2half(a0.z), __float2half(a0.w),
                    __float2half(a1.x), __float2half(a1.y), __float2half(a1.z), __float2half(a1.w)};
    *(float4*)&As[am * 40 + akq] = *(float4*)o8;
#pragma unroll
    for (int h2 = 0; h2 < 2; ++h2) {
      int krr = bkr + h2 * 16;
      f16x8 bv = *(const f16x8*)(Bh + (size_t)(k0 + krr) * 2048 + n0 + bnc * 8);
#pragma unroll
      for (int e = 0; e < 8; ++e) Bs[(bnc * 8 + e) * 40 + krr] = (__half)(float)bv[e];
    }
    __syncthreads();
    f16x8 af = *(const f16x8*)&As[(w * 16 + rl) * 40 + kg * 8];
#pragma unroll
    for (int nn = 0; nn < 8; ++nn) {
      f16x8 bf = *(const f16x8*)&Bs[(nn * 16 + rl) * 40 + kg * 8];
      acc[nn] = __builtin_amdgcn_mfma_f32_16x16x32_f16(af, bf, acc[nn], 0, 0, 0);
    }
    __syncthreads();
  }

  if (blockIdx.y < 8) {
#pragma unroll
    for (int nn = 0; nn < 8; ++nn)
#pragma unroll
      for (int r = 0; r < 4; ++r) {
        int m = m0 + w * 16 + kg * 4 + r;
        kpre[(size_t)m * 1024 + n0 + nn * 16 + rl] = __float2half(acc[nn][r]);
      }
  } else {
    int b = m0 >> 7;
    int nlb = n0 - 1024;
#pragma unroll
    for (int nn = 0; nn < 8; ++nn)
#pragma unroll
      for (int r = 0; r < 4; ++r) {
        int s = (m0 & 127) + w * 16 + kg * 4 + r;
        int nl = nlb + nn * 16 + rl;
        cwt[((size_t)(b << 10) + nl) * 128 + s] = __float2half(acc[nn][r]);
      }
  }
}

// ---------------- split arrive/wait padded half-barrier ----------------
// Per half (128 blocks): B = bar + half*4096 (u32). Every word on its own
// 256B line:
//   part_ctr[p] = B[p*64]        p=0..7   (16 blocks each)
//   glob_ctr    = B[512]
//   part_rel[p] = B[1024+p*64]
//   poison      = B[2048]
//   alpha flag[b] = B[2304+b*64] b=0..15  (gen = t+1, monotone)

__device__ __forceinline__ void bar_arrive(unsigned* B, int hblk, unsigned gen) {
  __syncthreads();   // all block stores drained (compiler emits vmcnt before s_barrier)
  if (threadIdx.x == 0) {
    int p = hblk >> 4;
    unsigned a = __hip_atomic_fetch_add(&B[p * 64], 1u,
                                        __ATOMIC_RELAXED, __HIP_MEMORY_SCOPE_AGENT);
    if (a == gen * 16u - 1u) {
      unsigned g2 = __hip_atomic_fetch_add(&B[512], 1u,
                                           __ATOMIC_RELAXED, __HIP_MEMORY_SCOPE_AGENT);
      if (g2 == gen * 8u - 1u) {
#pragma unroll
        for (int q = 0; q < 8; ++q) astore32(&B[1024 + q * 64], gen);
      }
    }
  }
}

__device__ __forceinline__ void bar_wait(unsigned* B, int hblk, unsigned gen) {
  if (threadIdx.x == 0) {
    int p = hblk >> 4;
    unsigned spins = 0;
    while (aload32u(&B[1024 + p * 64]) < gen) {
      __builtin_amdgcn_s_sleep(1);
      if ((++spins & 255u) == 0u) {
        if (aload32u(&B[2048]) != 0u) break;
        if (spins > 2000000u) { astore32(&B[2048], 1u); break; }
      }
    }
    asm volatile("" ::: "memory");
  }
  __syncthreads();
}

__device__ __forceinline__ void halfbar(unsigned* B, int hblk, unsigned gen) {
  bar_arrive(B, hblk, gen);
  bar_wait(B, hblk, gen);
}

// ---------------- persistent kernel ----------------
// Two independent half-grids: half = blk>>7 (batches half*16..+15), hblk=blk&127.
// LDS map:
//  A: inp 16x6160B [0,98560) | redA [98560,104704)
//  BC: hsl 16x2064B [0,33024) | redC [33024,41216) | al [41216,49664)
//      | cx [49664,51712) | scL [51712,52224) | wred [52224,52240)
//  BC->A window: x/h written into inp after bar-end arrive's syncthreads.

__global__ __launch_bounds__(512, 2) void k_persist(
    const __half* __restrict__ xf, const f16x8* __restrict__ wp,
    const f16x8* __restrict__ whp, const __half* __restrict__ kpre,
    const __half* __restrict__ cwt, const float* __restrict__ biasr,
    const float* __restrict__ bout, __half* __restrict__ hbuf,
    __half* __restrict__ attn, float* __restrict__ alpha,
    float* __restrict__ out, unsigned* __restrict__ bar) {
  __shared__ __align__(16) char smem[104704];
  int tid = threadIdx.x;
  int blk = blockIdx.x;
  int half = blk >> 7, hblk = blk & 127;
  unsigned* Bbar = bar + half * 4096;
  int w = tid >> 6, l = tid & 63;
  int rl = l & 15, kg = l >> 4;

  // ---- phase A roles
  int rblk = hblk, bh2 = half;
  int mh = w & 1, kq = w >> 1;
  int mtA = rblk * 2 + mh;

  f16x8 wa[24];
#pragma unroll
  for (int q = 0; q < 24; ++q)
    wa[q] = wp[((size_t)mtA * 96 + kq * 24 + q) * 64 + l];

  // ---- phase BC roles: nt pairs duplicate (hblk even/odd)
  int nt = hblk >> 1, bhc = half;
  f16x8 wc[4];
#pragma unroll
  for (int q = 0; q < 4; ++q)
    wc[q] = whp[(((size_t)nt * 32) + w * 4 + q) * 64 + l];

  float4 bvA = *(const float4*)&biasr[mtA * 16 + kg * 4];   // w<2
  float4 bo4 = *(const float4*)&bout[nt * 16 + kg * 4];     // w==0

  float creg = 0.f;

  __half* inp = (__half*)smem;
  float* redA = (float*)(smem + 98560);
  __half* hsl = (__half*)smem;
  float* redC = (float*)(smem + 33024);
  float* al   = (float*)(smem + 41216);
  float* cx   = (float*)(smem + 49664);
  float* scL  = (float*)(smem + 51712);
  float* wred = (float*)(smem + 52224);

  // alpha-owner roles: 16 owners per half (hblk multiple of 8)
  bool isOwner = (hblk & 7) == 0;
  int blOwn = hblk >> 3;                 // local batch 0..15
  int bown = half * 16 + blOwn;          // global batch

  // phase C ctx roles
  int nl2 = tid & 15, bl2 = (tid >> 4) & 15, sh = tid >> 8;

  // phase A staging roles
  int b0 = tid >> 5, c0 = tid & 31;
  int bbA = bh2 * 16 + b0;

  // pre-loop: stage x(t=0) and h=0 into inp
  {
    char* drow = (char*)inp + b0 * 6160;
    const __half* xrow = xf + ((size_t)bbA * 128 + 0) * 1024;
    float4 z = {0.f, 0.f, 0.f, 0.f};
#pragma unroll
    for (int j = 0; j < 4; ++j) {
      float4 xv = *(const float4*)(xrow + (c0 + 32 * j) * 8);
      *(float4*)(drow + (c0 + 32 * j) * 16) = xv;
      *(float4*)(drow + (256 + c0 + 32 * j) * 16) = z;
    }
  }

  for (int t = 0; t < 128; ++t) {
    int cur = t & 1;
    __half* hcur = hbuf + cur * 32768;

    // ======== phase A: attn staging + gates MFMA + cell ========
    {
      char* drow = (char*)inp + b0 * 6160;
      if (t == 0) {
        float4 z = {0.f, 0.f, 0.f, 0.f};
#pragma unroll
        for (int j = 0; j < 4; ++j)
          *(float4*)(drow + (128 + c0 + 32 * j) * 16) = z;
      } else {
        const __half* arow = attn + ((size_t)bbA << 10);
        float4 av[4];
#pragma unroll
        for (int j = 0; j < 4; ++j)
          av[j] = aload128(arow + (c0 + 32 * j) * 8);   // coherent
#pragma unroll
        for (int j = 0; j < 4; ++j)
          *(float4*)(drow + (128 + c0 + 32 * j) * 16) = av[j];
      }
      __syncthreads();
      f32x4 acc0 = {0, 0, 0, 0}, acc1 = {0, 0, 0, 0};
      const char* brow = (const char*)inp + rl * 6160 + kg * 16;
#pragma unroll
      for (int q = 0; q < 24; q += 2) {
        f16x8 bf0 = *(const f16x8*)(brow + (kq * 24 + q) * 64);
        f16x8 bf1 = *(const f16x8*)(brow + (kq * 24 + q + 1) * 64);
        acc0 = __builtin_amdgcn_mfma_f32_16x16x32_f16(wa[q], bf0, acc0, 0, 0, 0);
        acc1 = __builtin_amdgcn_mfma_f32_16x16x32_f16(wa[q + 1], bf1, acc1, 0, 0, 0);
      }
      f32x4 acc;
      acc[0] = acc0[0] + acc1[0]; acc[1] = acc0[1] + acc1[1];
      acc[2] = acc0[2] + acc1[2]; acc[3] = acc0[3] + acc1[3];
      if (kq >= 1) *(f32x4*)&redA[(((kq - 1) * 2 + mh) * 64 + l) * 4] = acc;
      __syncthreads();
      if (w < 2) {   // kq==0, mh = w
#pragma unroll
        for (int p = 0; p < 3; ++p) {
          f32x4 o = *(f32x4*)&redA[((p * 2 + mh) * 64 + l) * 4];
          acc[0] += o[0]; acc[1] += o[1]; acc[2] += o[2]; acc[3] += o[3];
        }
        float gi = acc[0] + bvA.x;
        float gf = acc[1] + bvA.y;
        float gg = acc[2] + bvA.z;
        float go = acc[3] + bvA.w;
        float si = 1.f / (1.f + __expf(-gi));
        float sf = 1.f / (1.f + __expf(-gf));
        float so = 1.f / (1.f + __expf(-go));
        creg = sf * creg + si * tanhf(gg);
        int u = rblk * 8 + mh * 4 + kg;
        int b = bh2 * 16 + rl;
        __half hv = __float2half(so * tanhf(creg));
        astore16(&hcur[((size_t)b << 10) + u], *(unsigned short*)&hv);   // coherent
      }
    }
    halfbar(Bbar, hblk, 2 * t + 1);

    // ======== phase BC: h stage; owner alpha; h-proj; poll; ctx; out ========
    {
      // stage h for 16 batches (coherent)
#pragma unroll
      for (int i2 = 0; i2 < 4; ++i2) {
        int f = i2 * 512 + tid;
        int b2 = f >> 7, u2 = f & 127;
        const __half* s = hcur + (((size_t)bhc * 16 + b2) << 10) + u2 * 8;
        char* d = (char*)hsl + b2 * 2064 + u2 * 16;
        ((u64*)d)[0] = aload64(s);
        ((u64*)d)[1] = aload64(s + 4);
      }
      __syncthreads();

      if (isOwner) {
        // scores for batch bown: 128 rows x 4 threads (256 k each)
        int row = tid >> 2, kq2 = tid & 3;
        const __half* krow = kpre + ((size_t)(bown * 128 + row) << 10) + kq2 * 256;
        const char* hrow = (const char*)hsl + blOwn * 2064 + kq2 * 512;
        float p = 0.f;
#pragma unroll
        for (int it = 0; it < 32; ++it) {
          f16x8 kv = *(const f16x8*)(krow + it * 8);
          f16x8 hv = *(const f16x8*)(hrow + it * 16);
#pragma unroll
          for (int e = 0; e < 8; ++e) p = fmaf((float)kv[e], (float)hv[e], p);
        }
        p += __shfl_xor(p, 1);
        p += __shfl_xor(p, 2);
        if (kq2 == 0) scL[row] = p;
        __syncthreads();
        float ev = 0.f, vs = 0.f;
        if (tid < 128) {
          float v = scL[tid];
          float m = v;
#pragma unroll
          for (int off = 32; off; off >>= 1) m = fmaxf(m, __shfl_xor(m, off));
          if ((tid & 63) == 0) wred[tid >> 6] = m;
          vs = v;
        }
        __syncthreads();
        if (tid < 128) {
          float m = fmaxf(wred[0], wred[1]);
          ev = __expf(vs - m);
          float s2 = ev;
#pragma unroll
          for (int off = 32; off; off >>= 1) s2 += __shfl_xor(s2, off);
          if ((tid & 63) == 0) wred[2 + (tid >> 6)] = s2;
        }
        __syncthreads();
        if (tid < 128) {
          float s2 = wred[2] + wred[3];
          astore32(&alpha[bown * 128 + tid], __float_as_uint(ev / s2));
        }
        __syncthreads();   // drains all waves' alpha stores (vmcnt before s_barrier)
        if (tid == 0) {
          asm volatile("s_waitcnt vmcnt(0)" ::: "memory");
          astore32(&Bbar[2304 + blOwn * 64], (unsigned)(t + 1));
        }
      }

      // h-proj MFMA -> redC (all blocks; overlaps owners' score latency)
      {
        f32x4 acc2 = {0, 0, 0, 0};
        const char* brow2 = (const char*)hsl + rl * 2064 + kg * 16;
#pragma unroll
        for (int q = 0; q < 4; ++q) {
          f16x8 bf = *(const f16x8*)(brow2 + (w * 4 + q) * 64);
          acc2 = __builtin_amdgcn_mfma_f32_16x16x32_f16(wc[q], bf, acc2, 0, 0, 0);
        }
        *(f32x4*)&redC[(w * 64 + l) * 4] = acc2;
      }

      // poll alpha flags (lanes 0..15), then read alpha -> al
      if (tid < 16) {
        const unsigned* fl = &Bbar[2304 + tid * 64];
        unsigned spins = 0;
        while (aload32u(fl) < (unsigned)(t + 1)) {
          __builtin_amdgcn_s_sleep(1);
          if ((++spins & 255u) == 0u) {
            if (aload32u(&Bbar[2048]) != 0u) break;
            if (spins > 2000000u) { astore32(&Bbar[2048], 1u); break; }
          }
        }
      }
      __syncthreads();
      {
        int f4 = tid * 4, bl = f4 >> 7, lj = f4 & 127;
        float4 av = aload128(&alpha[((size_t)(half * 16 + bl)) * 128 + lj]);   // coherent
        *(float4*)&al[bl * 132 + lj] = av;
      }
      __syncthreads();
      // ctx partials: (nl2, bl2, sh), cwt per-step coalesced loads
      {
        const __half* crow = cwt + (((size_t)(bhc * 16 + bl2) << 10) + nt * 16 + nl2) * 128 + sh * 64;
        const float* arow2 = &al[bl2 * 132 + sh * 64];
        float pc = 0.f;
#pragma unroll
        for (int s2 = 0; s2 < 64; s2 += 8) {
          f16x8 cv = *(const f16x8*)(crow + s2);
#pragma unroll
          for (int e = 0; e < 8; ++e) pc = fmaf(arow2[s2 + e], (float)cv[e], pc);
        }
        cx[sh * 256 + bl2 * 16 + nl2] = pc;
      }
      __syncthreads();
      if (w == 0) {
        f32x4 acc2 = {0, 0, 0, 0};
#pragma unroll
        for (int p3 = 0; p3 < 8; ++p3) {
          f32x4 o = *(f32x4*)&redC[(p3 * 64 + l) * 4];
          acc2[0] += o[0]; acc2[1] += o[1]; acc2[2] += o[2]; acc2[3] += o[3];
        }
        int bfin = bhc * 16 + rl;
        int n0 = nt * 16 + kg * 4;
        float vo[4];
#pragma unroll
        for (int r = 0; r < 4; ++r) {
          float cv2 = cx[rl * 16 + kg * 4 + r] + cx[256 + rl * 16 + kg * 4 + r];
          float bb2 = (r == 0) ? bo4.x : (r == 1) ? bo4.y : (r == 2) ? bo4.z : bo4.w;
          vo[r] = tanhf(acc2[r] + cv2 + bb2);
        }
        __half o4[4] = {__float2half(vo[0]), __float2half(vo[1]),
                        __float2half(vo[2]), __float2half(vo[3])};
        astore64(&attn[((size_t)bfin << 10) + n0], *(u64*)o4);   // coherent
        float4 ov = {vo[0], vo[1], vo[2], vo[3]};
        *(float4*)&out[(((size_t)bfin * 128 + t) << 10) + n0] = ov;
      }
    }
    bar_arrive(Bbar, hblk, 2 * t + 2);
    // bar-end window: preload x_{t+1} + h_t and stage into inp LDS
    if (t < 127) {
      char* drow = (char*)inp + b0 * 6160;
      const __half* xrow = xf + ((size_t)bbA * 128 + (t + 1)) * 1024;
      const __half* hrow = hcur + ((size_t)bbA << 10);
#pragma unroll
      for (int j = 0; j < 4; ++j) {
        float4 xv = *(const float4*)(xrow + (c0 + 32 * j) * 8);
        float4 hv = aload128(hrow + (c0 + 32 * j) * 8);
        *(float4*)(drow + (c0 + 32 * j) * 16) = xv;
        *(float4*)(drow + (256 + c0 + 32 * j) * 16) = hv;
      }
    }
    bar_wait(Bbar, hblk, 2 * t + 2);
  }
}

// ---------------- launcher ----------------

extern "C" void kernel_launch(void* const* d_in, const int* in_sizes, int n_in,
                              void* d_out, int out_size, void* d_ws, size_t ws_size,
                              hipStream_t stream) {
  const float* x    = (const float*)d_in[0];
  const float* ctxp = (const float*)d_in[1];
  const float* wih  = (const float*)d_in[2];
  const float* whh  = (const float*)d_in[3];
  const float* bih  = (const float*)d_in[4];
  const float* bhh  = (const float*)d_in[5];
  const float* wq   = (const float*)d_in[6];
  const float* wout = (const float*)d_in[7];
  const float* bo   = (const float*)d_in[8];
  float* out = (float*)d_out;
  char* ws = (char*)d_ws;

  __half* xf    = (__half*)(ws + OFF_XF16);
  __half* wpq   = (__half*)(ws + OFF_WP);
  __half* whpq  = (__half*)(ws + OFF_WHP);
  __half* bcat  = (__half*)(ws + OFF_BCAT);
  __half* kpre  = (__half*)(ws + OFF_KPRE);
  __half* cwt   = (__half*)(ws + OFF_CWT);
  float*  biasr = (float*)(ws + OFF_BIASR);
  __half* hbuf  = (__half*)(ws + OFF_H2);
  __half* attn  = (__half*)(ws + OFF_ATTN);
  float*  alp   = (float*)(ws + OFF_SC);
  unsigned* bar = (unsigned*)(ws + OFF_BAR);

  hipMemsetAsync(ws + OFF_BAR, 0, 32768, stream);

  hipLaunchKernelGGL(k_cvt_x, dim3(4096), dim3(256), 0, stream, x, xf);
  hipLaunchKernelGGL(k_build_bcat, dim3(8, 1024), dim3(256), 0, stream, wq, wout, bcat);
  hipLaunchKernelGGL(k_pack_wp, dim3(256, 24), dim3(256), 0, stream, wih, whh, wpq);
  hipLaunchKernelGGL(k_pack_whp, dim3(64, 8), dim3(256), 0, stream, wout, whpq);
  hipLaunchKernelGGL(k_bias_r, dim3(16), dim3(256), 0, stream, bih, bhh, biasr);
  hipLaunchKernelGGL(k_pregemm, dim3(64, 16), dim3(256), 0, stream, ctxp, bcat, kpre, cwt);

  const f16x8* wpv = (const f16x8*)wpq;
  const f16x8* whpv = (const f16x8*)whpq;
  const __half* xfc = xf;
  const __half* kprec = kpre;
  const __half* cwtc = cwt;
  const float* biasrc = biasr;
  const float* boc = bo;
  void* args[] = {(void*)&xfc, (void*)&wpv, (void*)&whpv, (void*)&kprec, (void*)&cwtc,
                  (void*)&biasrc, (void*)&boc, (void*)&hbuf, (void*)&attn, (void*)&alp,
                  (void*)&out, (void*)&bar};
  hipLaunchCooperativeKernel((void*)k_persist, dim3(256), dim3(512), args, 0, stream);
}

// Round 11
// 1609.583 us; speedup vs baseline: 2.4799x; 2.4799x over previous
//
#include <hip/hip_runtime.h>
#include <hip/hip_fp16.h>

// B=32, T=128, Din=H=C=1024, S=128.
// R11: R9 structure (3 split-arrive/wait barriers/step, distributed scores,
// flat release, MFMA pregemm) + phase-BC pair-split by batch: pair member
// d=hblk&1 owns 8 of the half's 16 batches (R9's nt-pairs duplicated ALL
// phase-BC work). Halves h staging (32->16+2KB), ctx cwt (64->32KB),
// softmax rows (16->8), dedups attn/out writes.
// R10's owner+flag handoff REVERTED (falsified: owner serialization +
// 128-pollers/line flag storm -> 3,737us, FETCH 792MB).
//
// MFMA 16x16x32_f16 layout (guide §3, m89-verified):
//   A: lane l, elem j -> A[l&15][(l>>4)*8+j]
//   B: lane l, elem j -> B[(l>>4)*8+j][l&15]
//   D: lane l, reg  r -> D[(l>>4)*4+r][l&15]

typedef _Float16 f16x8 __attribute__((ext_vector_type(8)));
typedef float f32x4 __attribute__((ext_vector_type(4)));
typedef unsigned long long u64;

// ---- workspace layout (bytes) ----
#define OFF_XF16  ((size_t)0)           // [32][128][1024] f16     8,388,608
#define OFF_WP    ((size_t)8388608)     // [256][96][64][8] f16   25,165,824
#define OFF_WHP   ((size_t)33554432)    // [64][32][64][8] f16     2,097,152
#define OFF_BCAT  ((size_t)35651584)    // [1024][2048] f16        4,194,304
#define OFF_KPRE  ((size_t)39845888)    // [4096][1024] f16 row-major 8,388,608
#define OFF_CWT   ((size_t)48234496)    // [32][1024][128] f16     8,388,608
#define OFF_BIASR ((size_t)56623104)    // [4096] f32                 16,384
#define OFF_H2    ((size_t)56770560)    // [2][32][1024] f16         131,072
#define OFF_ATTN  ((size_t)56901632)    // [32][1024] f16             65,536
#define OFF_SC    ((size_t)56967168)    // [32][128] f32              16,384
#define OFF_BAR   ((size_t)56983552)    // 32 KB barrier state (2 halves x 16KB)

// ---- agent-scope coherent access helpers (bypass non-coherent L2) ----
__device__ __forceinline__ u64 aload64(const void* p) {
  return __hip_atomic_load((const u64*)p, __ATOMIC_RELAXED, __HIP_MEMORY_SCOPE_AGENT);
}
__device__ __forceinline__ unsigned aload32u(const unsigned* p) {
  return __hip_atomic_load(p, __ATOMIC_RELAXED, __HIP_MEMORY_SCOPE_AGENT);
}
__device__ __forceinline__ void astore32(void* p, unsigned v) {
  __hip_atomic_store((unsigned*)p, v, __ATOMIC_RELAXED, __HIP_MEMORY_SCOPE_AGENT);
}
__device__ __forceinline__ void astore64(void* p, u64 v) {
  __hip_atomic_store((u64*)p, v, __ATOMIC_RELAXED, __HIP_MEMORY_SCOPE_AGENT);
}
__device__ __forceinline__ void astore16(void* p, unsigned short v) {
  __hip_atomic_store((unsigned short*)p, v, __ATOMIC_RELAXED, __HIP_MEMORY_SCOPE_AGENT);
}
__device__ __forceinline__ float4 aload128(const void* p) {
  float4 v;
  ((u64*)&v)[0] = aload64(p);
  ((u64*)&v)[1] = aload64((const char*)p + 8);
  return v;
}

// ---------------- one-time kernels ----------------

__global__ __launch_bounds__(256) void k_cvt_x(const float* __restrict__ x, __half* __restrict__ xf) {
  int i = blockIdx.x * 256 + threadIdx.x;
  float4 v = ((const float4*)x)[i];
  __half h4[4] = {__float2half(v.x), __float2half(v.y), __float2half(v.z), __float2half(v.w)};
  ((float2*)xf)[i] = *(float2*)h4;
}

__global__ __launch_bounds__(256) void k_build_bcat(const float* __restrict__ wq,
                                                    const float* __restrict__ wout,
                                                    __half* __restrict__ bcat) {
  int j = blockIdx.x * 256 + threadIdx.x;
  int c = blockIdx.y;
  float v = (j < 1024) ? wq[c * 1024 + j] : wout[(size_t)(j - 1024) * 2048 + c];
  bcat[c * 2048 + j] = __float2half(v);
}

// pack gate weights into MFMA A-fragment stream: wp[mt][ks][l][8]
// packed row r' = mt*16 + (l&15); original row = gate*1024 + u, r' = u*4+gate
__global__ __launch_bounds__(256) void k_pack_wp(const float* __restrict__ wih,
                                                 const float* __restrict__ whh,
                                                 __half* __restrict__ wpo) {
  int mt = blockIdx.x;
  int tid = threadIdx.x;
  int ks = blockIdx.y * 4 + (tid >> 6);
  int l = tid & 63;
  int rp = mt * 16 + (l & 15);
  int u = rp >> 2, g = rp & 3;
  int row = g * 1024 + u;
  int k = ks * 32 + (l >> 4) * 8;
  const float* src = (k < 2048) ? (wih + (size_t)row * 2048 + k)
                                : (whh + (size_t)row * 1024 + (k - 2048));
  float4 a = *(const float4*)src;
  float4 b = *(const float4*)(src + 4);
  __half o[8] = {__float2half(a.x), __float2half(a.y), __float2half(a.z), __float2half(a.w),
                 __float2half(b.x), __float2half(b.y), __float2half(b.z), __float2half(b.w)};
  *(float4*)(wpo + (((size_t)mt * 96 + ks) * 64 + l) * 8) = *(float4*)o;
}

__global__ __launch_bounds__(256) void k_pack_whp(const float* __restrict__ wout,
                                                  __half* __restrict__ wpo) {
  int nt = blockIdx.x;
  int tid = threadIdx.x;
  int ks = blockIdx.y * 4 + (tid >> 6);
  int l = tid & 63;
  int row = nt * 16 + (l & 15);
  int k = ks * 32 + (l >> 4) * 8;
  const float* src = wout + (size_t)row * 2048 + 1024 + k;
  float4 a = *(const float4*)src;
  float4 b = *(const float4*)(src + 4);
  __half o[8] = {__float2half(a.x), __float2half(a.y), __float2half(a.z), __float2half(a.w),
                 __float2half(b.x), __float2half(b.y), __float2half(b.z), __float2half(b.w)};
  *(float4*)(wpo + (((size_t)nt * 32 + ks) * 64 + l) * 8) = *(float4*)o;
}

__global__ __launch_bounds__(256) void k_bias_r(const float* __restrict__ bih,
                                                const float* __restrict__ bhh,
                                                float* __restrict__ biasr) {
  int i = blockIdx.x * 256 + threadIdx.x;
  int u = i >> 2, g = i & 3;
  biasr[i] = bih[g * 1024 + u] + bhh[g * 1024 + u];
}

// MFMA precompute GEMM: [4096 x 1024] fp32 @ [1024 x 2048] f16.
// Block = 64m x 128n, 256 thr (4 waves); wave w owns m-subtile w, 8 n-subtiles.
// n0<1024 -> kpre[m][n] row-major ; else -> cwt[b][n-1024][s], m=b*128+s.
__global__ __launch_bounds__(256) void k_pregemm(const float* __restrict__ Af,
                                                 const __half* __restrict__ Bh,
                                                 __half* __restrict__ kpre,
                                                 __half* __restrict__ cwt) {
  __shared__ __half As[64 * 40];    // [m][k], stride 40 halves
  __shared__ __half Bs[128 * 40];   // [n][k] transposed, stride 40
  int tid = threadIdx.x;
  int w = tid >> 6, l = tid & 63;
  int rl = l & 15, kg = l >> 4;
  int m0 = blockIdx.x * 64;
  int n0 = blockIdx.y * 128;
  f32x4 acc[8] = {};

  int am = tid >> 2, akq = (tid & 3) * 8;       // A staging: row, k-offset
  int bkr = tid >> 4, bnc = tid & 15;           // B staging: k-row, n-octet

  for (int k0 = 0; k0 < 1024; k0 += 32) {
    const float* ap = Af + (size_t)(m0 + am) * 1024 + k0 + akq;
    float4 a0 = *(const float4*)ap;
    float4 a1 = *(const float4*)(ap + 4);
    __half o8[8] = {__float2half(a0.x), __float2half(a0.y), __float2half(a0.z), __float2half(a0.w),
                    __float2half(a1.x), __float2half(a1.y), __float2half(a1.z), __float2half(a1.w)};
    *(float4*)&As[am * 40 + akq] = *(float4*)o8;
#pragma unroll
    for (int h2 = 0; h2 < 2; ++h2) {
      int krr = bkr + h2 * 16;
      f16x8 bv = *(const f16x8*)(Bh + (size_t)(k0 + krr) * 2048 + n0 + bnc * 8);
#pragma unroll
      for (int e = 0; e < 8; ++e) Bs[(bnc * 8 + e) * 40 + krr] = (__half)(float)bv[e];
    }
    __syncthreads();
    f16x8 af = *(const f16x8*)&As[(w * 16 + rl) * 40 + kg * 8];
#pragma unroll
    for (int nn = 0; nn < 8; ++nn) {
      f16x8 bf = *(const f16x8*)&Bs[(nn * 16 + rl) * 40 + kg * 8];
      acc[nn] = __builtin_amdgcn_mfma_f32_16x16x32_f16(af, bf, acc[nn], 0, 0, 0);
    }
    __syncthreads();
  }

  if (blockIdx.y < 8) {
#pragma unroll
    for (int nn = 0; nn < 8; ++nn)
#pragma unroll
      for (int r = 0; r < 4; ++r) {
        int m = m0 + w * 16 + kg * 4 + r;
        kpre[(size_t)m * 1024 + n0 + nn * 16 + rl] = __float2half(acc[nn][r]);
      }
  } else {
    int b = m0 >> 7;
    int nlb = n0 - 1024;
#pragma unroll
    for (int nn = 0; nn < 8; ++nn)
#pragma unroll
      for (int r = 0; r < 4; ++r) {
        int s = (m0 & 127) + w * 16 + kg * 4 + r;
        int nl = nlb + nn * 16 + rl;
        cwt[((size_t)(b << 10) + nl) * 128 + s] = __float2half(acc[nn][r]);
      }
  }
}

// ---------------- split arrive/wait padded half-barrier ----------------
// Per half (128 blocks): B = bar + half*4096 (u32). Every word on its own
// 256B line:
//   part_ctr[p] = B[p*64]        p=0..7   (16 blocks each)
//   glob_ctr    = B[512]
//   part_rel[p] = B[1024+p*64]
//   poison      = B[2048]
// Last arriver (global ctr hits gen*8) writes all 8 part_rel words.

__device__ __forceinline__ void bar_arrive(unsigned* B, int hblk, unsigned gen) {
  __syncthreads();   // all block stores drained (compiler emits vmcnt before s_barrier)
  if (threadIdx.x == 0) {
    int p = hblk >> 4;
    unsigned a = __hip_atomic_fetch_add(&B[p * 64], 1u,
                                        __ATOMIC_RELAXED, __HIP_MEMORY_SCOPE_AGENT);
    if (a == gen * 16u - 1u) {
      unsigned g2 = __hip_atomic_fetch_add(&B[512], 1u,
                                           __ATOMIC_RELAXED, __HIP_MEMORY_SCOPE_AGENT);
      if (g2 == gen * 8u - 1u) {
#pragma unroll
        for (int q = 0; q < 8; ++q) astore32(&B[1024 + q * 64], gen);
      }
    }
  }
}

__device__ __forceinline__ void bar_wait(unsigned* B, int hblk, unsigned gen) {
  if (threadIdx.x == 0) {
    int p = hblk >> 4;
    unsigned spins = 0;
    while (aload32u(&B[1024 + p * 64]) < gen) {
      __builtin_amdgcn_s_sleep(1);
      if ((++spins & 255u) == 0u) {
        if (aload32u(&B[2048]) != 0u) break;
        if (spins > 2000000u) { astore32(&B[2048], 1u); break; }
      }
    }
    asm volatile("" ::: "memory");
  }
  __syncthreads();
}

__device__ __forceinline__ void halfbar(unsigned* B, int hblk, unsigned gen) {
  bar_arrive(B, hblk, gen);
  bar_wait(B, hblk, gen);
}

// ---------------- persistent kernel ----------------
// Two independent half-grids: half = blk>>7 (batches half*16..+15), hblk=blk&127.
// Phase BC pair-split: d = hblk&1 owns local batches d*8..d*8+7; nt = hblk>>1.
// LDS map:
//  A: inp 16x6160B [0,98560) | redA [98560,104704)
//  BC: hsl 16x2064B [0,33024) (rows 0..7 used) | redC [33024,41216)
//      | al [41216,45440) 8x132 f32 | cx [45440,47488) 512 f32
//      | hs2 [47488,49536) 2KB
//  BC->A window: x/h written into inp after bar-end arrive's syncthreads.

__global__ __launch_bounds__(512, 2) void k_persist(
    const __half* __restrict__ xf, const f16x8* __restrict__ wp,
    const f16x8* __restrict__ whp, const __half* __restrict__ kpre,
    const __half* __restrict__ cwt, const float* __restrict__ biasr,
    const float* __restrict__ bout, __half* __restrict__ hbuf,
    __half* __restrict__ attn, float* __restrict__ scores,
    float* __restrict__ out, unsigned* __restrict__ bar) {
  __shared__ __align__(16) char smem[104704];
  int tid = threadIdx.x;
  int blk = blockIdx.x;
  int half = blk >> 7, hblk = blk & 127;
  unsigned* Bbar = bar + half * 4096;
  int w = tid >> 6, l = tid & 63;
  int rl = l & 15, kg = l >> 4;

  // ---- phase A roles
  int rblk = hblk, bh2 = half;
  int mh = w & 1, kq = w >> 1;
  int mtA = rblk * 2 + mh;

  f16x8 wa[24];
#pragma unroll
  for (int q = 0; q < 24; ++q)
    wa[q] = wp[((size_t)mtA * 96 + kq * 24 + q) * 64 + l];

  // ---- phase BC roles: nt = hblk>>1, pair member d owns 8 batches
  int nt = hblk >> 1, bhc = half, d = hblk & 1;
  f16x8 wc[4];
#pragma unroll
  for (int q = 0; q < 4; ++q)
    wc[q] = whp[(((size_t)nt * 32) + w * 4 + q) * 64 + l];

  float4 bvA = *(const float4*)&biasr[mtA * 16 + kg * 4];   // w<2
  float4 bo4 = *(const float4*)&bout[nt * 16 + kg * 4];     // w==0

  float creg = 0.f;

  __half* inp = (__half*)smem;
  float* redA = (float*)(smem + 98560);
  __half* hsl = (__half*)smem;
  float* redC = (float*)(smem + 33024);
  float* al   = (float*)(smem + 41216);
  float* cx   = (float*)(smem + 45440);
  __half* hs2 = (__half*)(smem + 47488);

  // phase B roles: scores for batch bbB, row srB
  int bbB = half * 16 + (hblk >> 3), s0B = (hblk & 7) * 16;
  int srB = s0B + w * 2 + (l >> 5), lkB = l & 31;

  // phase C ctx roles: n, batch-octet member, s-quarter
  int nl2 = tid & 15, bl8 = (tid >> 4) & 7, sh = tid >> 7;

  // phase A staging roles
  int b0 = tid >> 5, c0 = tid & 31;
  int bbA = bh2 * 16 + b0;

  // pre-loop: stage x(t=0) and h=0 into inp
  {
    char* drow = (char*)inp + b0 * 6160;
    const __half* xrow = xf + ((size_t)bbA * 128 + 0) * 1024;
    float4 z = {0.f, 0.f, 0.f, 0.f};
#pragma unroll
    for (int j = 0; j < 4; ++j) {
      float4 xv = *(const float4*)(xrow + (c0 + 32 * j) * 8);
      *(float4*)(drow + (c0 + 32 * j) * 16) = xv;
      *(float4*)(drow + (256 + c0 + 32 * j) * 16) = z;
    }
  }

  for (int t = 0; t < 128; ++t) {
    int cur = t & 1;
    __half* hcur = hbuf + cur * 32768;

    // ======== phase A: attn staging + gates MFMA + cell ========
    {
      char* drow = (char*)inp + b0 * 6160;
      if (t == 0) {
        float4 z = {0.f, 0.f, 0.f, 0.f};
#pragma unroll
        for (int j = 0; j < 4; ++j)
          *(float4*)(drow + (128 + c0 + 32 * j) * 16) = z;
      } else {
        const __half* arow = attn + ((size_t)bbA << 10);
        float4 av[4];
#pragma unroll
        for (int j = 0; j < 4; ++j)
          av[j] = aload128(arow + (c0 + 32 * j) * 8);   // coherent
#pragma unroll
        for (int j = 0; j < 4; ++j)
          *(float4*)(drow + (128 + c0 + 32 * j) * 16) = av[j];
      }
      __syncthreads();
      f32x4 acc0 = {0, 0, 0, 0}, acc1 = {0, 0, 0, 0};
      const char* brow = (const char*)inp + rl * 6160 + kg * 16;
#pragma unroll
      for (int q = 0; q < 24; q += 2) {
        f16x8 bf0 = *(const f16x8*)(brow + (kq * 24 + q) * 64);
        f16x8 bf1 = *(const f16x8*)(brow + (kq * 24 + q + 1) * 64);
        acc0 = __builtin_amdgcn_mfma_f32_16x16x32_f16(wa[q], bf0, acc0, 0, 0, 0);
        acc1 = __builtin_amdgcn_mfma_f32_16x16x32_f16(wa[q + 1], bf1, acc1, 0, 0, 0);
      }
      f32x4 acc;
      acc[0] = acc0[0] + acc1[0]; acc[1] = acc0[1] + acc1[1];
      acc[2] = acc0[2] + acc1[2]; acc[3] = acc0[3] + acc1[3];
      if (kq >= 1) *(f32x4*)&redA[(((kq - 1) * 2 + mh) * 64 + l) * 4] = acc;
      __syncthreads();
      if (w < 2) {   // kq==0, mh = w
#pragma unroll
        for (int p = 0; p < 3; ++p) {
          f32x4 o = *(f32x4*)&redA[((p * 2 + mh) * 64 + l) * 4];
          acc[0] += o[0]; acc[1] += o[1]; acc[2] += o[2]; acc[3] += o[3];
        }
        float gi = acc[0] + bvA.x;
        float gf = acc[1] + bvA.y;
        float gg = acc[2] + bvA.z;
        float go = acc[3] + bvA.w;
        float si = 1.f / (1.f + __expf(-gi));
        float sf = 1.f / (1.f + __expf(-gf));
        float so = 1.f / (1.f + __expf(-go));
        creg = sf * creg + si * tanhf(gg);
        int u = rblk * 8 + mh * 4 + kg;
        int b = bh2 * 16 + rl;
        __half hv = __float2half(so * tanhf(creg));
        astore16(&hcur[((size_t)b << 10) + u], *(unsigned short*)&hv);   // coherent
      }
    }
    halfbar(Bbar, hblk, 3 * t + 1);

    // ======== phase B: stage h(8 batches)+hs2 + scores; h-proj in bar2 window ========
    {
      // stage h for this member's 8 batches (coherent)
#pragma unroll
      for (int i2 = 0; i2 < 2; ++i2) {
        int f = i2 * 512 + tid;
        int b2 = f >> 7, u2 = f & 127;
        const __half* s = hcur + (((size_t)(bhc * 16 + d * 8 + b2)) << 10) + u2 * 8;
        char* dd = (char*)hsl + b2 * 2064 + u2 * 16;
        ((u64*)dd)[0] = aload64(s);
        ((u64*)dd)[1] = aload64(s + 4);
      }
      // stage scores batch row (2 KB)
      if (tid < 128) {
        const __half* s = hcur + ((size_t)bbB << 10) + tid * 8;
        ((u64*)&hs2[tid * 8])[0] = aload64(s);
        ((u64*)&hs2[tid * 8])[1] = aload64(s + 4);
      }
      __syncthreads();
      // scores: row srB of batch bbB (kpre per-step coalesced loads)
      {
        const __half* krow = kpre + ((size_t)(bbB * 128 + srB) << 10);
        float p = 0.f;
#pragma unroll
        for (int it = 0; it < 4; ++it) {
          f16x8 kv = *(const f16x8*)(krow + it * 256 + lkB * 8);
          f16x8 hv = *(const f16x8*)&hs2[it * 256 + lkB * 8];
#pragma unroll
          for (int e = 0; e < 8; ++e) p = fmaf((float)kv[e], (float)hv[e], p);
        }
#pragma unroll
        for (int off = 16; off; off >>= 1) p += __shfl_xor(p, off);
        if (lkB == 0) astore32(&scores[bbB * 128 + srB], __float_as_uint(p));  // coherent
      }
    }
    bar_arrive(Bbar, hblk, 3 * t + 2);
    {
      // h-proj MFMA while barrier drains (B cols 0..7 valid = batches d*8..);
      // redC persists into phase C
      f32x4 acc2 = {0, 0, 0, 0};
      const char* brow2 = (const char*)hsl + rl * 2064 + kg * 16;
#pragma unroll
      for (int q = 0; q < 4; ++q) {
        f16x8 bf = *(const f16x8*)(brow2 + (w * 4 + q) * 64);
        acc2 = __builtin_amdgcn_mfma_f32_16x16x32_f16(wc[q], bf, acc2, 0, 0, 0);
      }
      *(f32x4*)&redC[(w * 64 + l) * 4] = acc2;
    }
    bar_wait(Bbar, hblk, 3 * t + 2);

    // ======== phase C: softmax(8) + ctx + combine + tanh ========
    {
      // softmax: 32 lanes per batch, 8 batches (coherent score reads)
      {
        int bl = tid >> 5, lj = tid & 31;
        if (bl < 8) {
          const float* srow = scores + (bhc * 16 + d * 8 + bl) * 128;
          float4 sv = aload128(srow + lj * 4);
          float m = fmaxf(fmaxf(sv.x, sv.y), fmaxf(sv.z, sv.w));
#pragma unroll
          for (int off = 16; off; off >>= 1) m = fmaxf(m, __shfl_xor(m, off));
          float e0 = __expf(sv.x - m), e1 = __expf(sv.y - m);
          float e2 = __expf(sv.z - m), e3 = __expf(sv.w - m);
          float s = e0 + e1 + e2 + e3;
#pragma unroll
          for (int off = 16; off; off >>= 1) s += __shfl_xor(s, off);
          float inv = 1.f / s;
          float4 av2 = {e0 * inv, e1 * inv, e2 * inv, e3 * inv};
          *(float4*)&al[bl * 132 + lj * 4] = av2;
        }
      }
      __syncthreads();
      // ctx partials: (nl2, bl8, sh) over 32 s each; cwt coalesced loads
      {
        const __half* crow = cwt + (((size_t)(bhc * 16 + d * 8 + bl8) << 10) + nt * 16 + nl2) * 128 + sh * 32;
        const float* arow2 = &al[bl8 * 132 + sh * 32];
        float pc = 0.f;
#pragma unroll
        for (int s2 = 0; s2 < 32; s2 += 8) {
          f16x8 cv = *(const f16x8*)(crow + s2);
#pragma unroll
          for (int e = 0; e < 8; ++e) pc = fmaf(arow2[s2 + e], (float)cv[e], pc);
        }
        cx[sh * 128 + bl8 * 16 + nl2] = pc;
      }
      __syncthreads();
      if (w == 0 && rl < 8) {
        f32x4 acc2 = {0, 0, 0, 0};
#pragma unroll
        for (int p3 = 0; p3 < 8; ++p3) {
          f32x4 o = *(f32x4*)&redC[(p3 * 64 + l) * 4];
          acc2[0] += o[0]; acc2[1] += o[1]; acc2[2] += o[2]; acc2[3] += o[3];
        }
        int bfin = bhc * 16 + d * 8 + rl;
        int n0 = nt * 16 + kg * 4;
        float vo[4];
#pragma unroll
        for (int r = 0; r < 4; ++r) {
          float cv2 = cx[0 * 128 + rl * 16 + kg * 4 + r] + cx[1 * 128 + rl * 16 + kg * 4 + r]
                    + cx[2 * 128 + rl * 16 + kg * 4 + r] + cx[3 * 128 + rl * 16 + kg * 4 + r];
          float bb2 = (r == 0) ? bo4.x : (r == 1) ? bo4.y : (r == 2) ? bo4.z : bo4.w;
          vo[r] = tanhf(acc2[r] + cv2 + bb2);
        }
        __half o4[4] = {__float2half(vo[0]), __float2half(vo[1]),
                        __float2half(vo[2]), __float2half(vo[3])};
        astore64(&attn[((size_t)bfin << 10) + n0], *(u64*)o4);   // coherent, unique writer
        float4 ov = {vo[0], vo[1], vo[2], vo[3]};
        *(float4*)&out[(((size_t)bfin * 128 + t) << 10) + n0] = ov;
      }
    }
    bar_arrive(Bbar, hblk, 3 * t + 3);
    // bar-end window: preload x_{t+1} + h_t and stage into inp LDS
    if (t < 127) {
      char* drow = (char*)inp + b0 * 6160;
      const __half* xrow = xf + ((size_t)bbA * 128 + (t + 1)) * 1024;
      const __half* hrow = hcur + ((size_t)bbA << 10);
#pragma unroll
      for (int j = 0; j < 4; ++j) {
        float4 xv = *(const float4*)(xrow + (c0 + 32 * j) * 8);
        float4 hv = aload128(hrow + (c0 + 32 * j) * 8);
        *(float4*)(drow + (c0 + 32 * j) * 16) = xv;
        *(float4*)(drow + (256 + c0 + 32 * j) * 16) = hv;
      }
    }
    bar_wait(Bbar, hblk, 3 * t + 3);
  }
}

// ---------------- launcher ----------------

extern "C" void kernel_launch(void* const* d_in, const int* in_sizes, int n_in,
                              void* d_out, int out_size, void* d_ws, size_t ws_size,
                              hipStream_t stream) {
  const float* x    = (const float*)d_in[0];
  const float* ctxp = (const float*)d_in[1];
  const float* wih  = (const float*)d_in[2];
  const float* whh  = (const float*)d_in[3];
  const float* bih  = (const float*)d_in[4];
  const float* bhh  = (const float*)d_in[5];
  const float* wq   = (const float*)d_in[6];
  const float* wout = (const float*)d_in[7];
  const float* bo   = (const float*)d_in[8];
  float* out = (float*)d_out;
  char* ws = (char*)d_ws;

  __half* xf    = (__half*)(ws + OFF_XF16);
  __half* wpq   = (__half*)(ws + OFF_WP);
  __half* whpq  = (__half*)(ws + OFF_WHP);
  __half* bcat  = (__half*)(ws + OFF_BCAT);
  __half* kpre  = (__half*)(ws + OFF_KPRE);
  __half* cwt   = (__half*)(ws + OFF_CWT);
  float*  biasr = (float*)(ws + OFF_BIASR);
  __half* hbuf  = (__half*)(ws + OFF_H2);
  __half* attn  = (__half*)(ws + OFF_ATTN);
  float*  sc    = (float*)(ws + OFF_SC);
  unsigned* bar = (unsigned*)(ws + OFF_BAR);

  hipMemsetAsync(ws + OFF_BAR, 0, 32768, stream);

  hipLaunchKernelGGL(k_cvt_x, dim3(4096), dim3(256), 0, stream, x, xf);
  hipLaunchKernelGGL(k_build_bcat, dim3(8, 1024), dim3(256), 0, stream, wq, wout, bcat);
  hipLaunchKernelGGL(k_pack_wp, dim3(256, 24), dim3(256), 0, stream, wih, whh, wpq);
  hipLaunchKernelGGL(k_pack_whp, dim3(64, 8), dim3(256), 0, stream, wout, whpq);
  hipLaunchKernelGGL(k_bias_r, dim3(16), dim3(256), 0, stream, bih, bhh, biasr);
  hipLaunchKernelGGL(k_pregemm, dim3(64, 16), dim3(256), 0, stream, ctxp, bcat, kpre, cwt);

  const f16x8* wpv = (const f16x8*)wpq;
  const f16x8* whpv = (const f16x8*)whpq;
  const __half* xfc = xf;
  const __half* kprec = kpre;
  const __half* cwtc = cwt;
  const float* biasrc = biasr;
  const float* boc = bo;
  void* args[] = {(void*)&xfc, (void*)&wpv, (void*)&whpv, (void*)&kprec, (void*)&cwtc,
                  (void*)&biasrc, (void*)&boc, (void*)&hbuf, (void*)&attn, (void*)&sc,
                  (void*)&out, (void*)&bar};
  hipLaunchCooperativeKernel((void*)k_persist, dim3(256), dim3(512), args, 0, stream);
}

// Round 12
// 1606.655 us; speedup vs baseline: 2.4845x; 1.0018x over previous
//
#include <hip/hip_runtime.h>
#include <hip/hip_fp16.h>

// B=32, T=128, Din=H=C=1024, S=128.
// R12: R11 + barrier-window LDS prefetch of the attention operands:
//  - kpreL (32KB, block's 16 score rows) staged coalesced in the bar1 window;
//    phase-B dot reads LDS.
//  - cwtL (34KB padded) staged coalesced in the bar2 window (overlapping
//    h-proj MFMA); phase-C ctx reads LDS (strides padded to <=2-way banks).
//  Both live in inp bytes [49664,84736) — lifetime chain desk-checked:
//  phaseA-read < kpreL-wr < phaseB-rd < cwtL-wr < phaseC-rd < bar3 x/h-wr.
//
// MFMA 16x16x32_f16 layout (guide §3, m89-verified):
//   A: lane l, elem j -> A[l&15][(l>>4)*8+j]
//   B: lane l, elem j -> B[(l>>4)*8+j][l&15]
//   D: lane l, reg  r -> D[(l>>4)*4+r][l&15]

typedef _Float16 f16x8 __attribute__((ext_vector_type(8)));
typedef float f32x4 __attribute__((ext_vector_type(4)));
typedef unsigned long long u64;

// ---- workspace layout (bytes) ----
#define OFF_XF16  ((size_t)0)           // [32][128][1024] f16     8,388,608
#define OFF_WP    ((size_t)8388608)     // [256][96][64][8] f16   25,165,824
#define OFF_WHP   ((size_t)33554432)    // [64][32][64][8] f16     2,097,152
#define OFF_BCAT  ((size_t)35651584)    // [1024][2048] f16        4,194,304
#define OFF_KPRE  ((size_t)39845888)    // [4096][1024] f16 row-major 8,388,608
#define OFF_CWT   ((size_t)48234496)    // [32][1024][128] f16     8,388,608
#define OFF_BIASR ((size_t)56623104)    // [4096] f32                 16,384
#define OFF_H2    ((size_t)56770560)    // [2][32][1024] f16         131,072
#define OFF_ATTN  ((size_t)56901632)    // [32][1024] f16             65,536
#define OFF_SC    ((size_t)56967168)    // [32][128] f32              16,384
#define OFF_BAR   ((size_t)56983552)    // 32 KB barrier state (2 halves x 16KB)

// LDS overlay offsets (inside smem[104704])
#define L_KPREL 49664   // 16 x 2048 B = 32,768 -> ends 82,432
#define L_CWTL  49664   // 8 x 4384 B = 35,072 -> ends 84,736 (pads: n 272, b 4384)

// ---- agent-scope coherent access helpers (bypass non-coherent L2) ----
__device__ __forceinline__ u64 aload64(const void* p) {
  return __hip_atomic_load((const u64*)p, __ATOMIC_RELAXED, __HIP_MEMORY_SCOPE_AGENT);
}
__device__ __forceinline__ unsigned aload32u(const unsigned* p) {
  return __hip_atomic_load(p, __ATOMIC_RELAXED, __HIP_MEMORY_SCOPE_AGENT);
}
__device__ __forceinline__ void astore32(void* p, unsigned v) {
  __hip_atomic_store((unsigned*)p, v, __ATOMIC_RELAXED, __HIP_MEMORY_SCOPE_AGENT);
}
__device__ __forceinline__ void astore64(void* p, u64 v) {
  __hip_atomic_store((u64*)p, v, __ATOMIC_RELAXED, __HIP_MEMORY_SCOPE_AGENT);
}
__device__ __forceinline__ void astore16(void* p, unsigned short v) {
  __hip_atomic_store((unsigned short*)p, v, __ATOMIC_RELAXED, __HIP_MEMORY_SCOPE_AGENT);
}
__device__ __forceinline__ float4 aload128(const void* p) {
  float4 v;
  ((u64*)&v)[0] = aload64(p);
  ((u64*)&v)[1] = aload64((const char*)p + 8);
  return v;
}

// ---------------- one-time kernels ----------------

__global__ __launch_bounds__(256) void k_cvt_x(const float* __restrict__ x, __half* __restrict__ xf) {
  int i = blockIdx.x * 256 + threadIdx.x;
  float4 v = ((const float4*)x)[i];
  __half h4[4] = {__float2half(v.x), __float2half(v.y), __float2half(v.z), __float2half(v.w)};
  ((float2*)xf)[i] = *(float2*)h4;
}

__global__ __launch_bounds__(256) void k_build_bcat(const float* __restrict__ wq,
                                                    const float* __restrict__ wout,
                                                    __half* __restrict__ bcat) {
  int j = blockIdx.x * 256 + threadIdx.x;
  int c = blockIdx.y;
  float v = (j < 1024) ? wq[c * 1024 + j] : wout[(size_t)(j - 1024) * 2048 + c];
  bcat[c * 2048 + j] = __float2half(v);
}

// pack gate weights into MFMA A-fragment stream: wp[mt][ks][l][8]
// packed row r' = mt*16 + (l&15); original row = gate*1024 + u, r' = u*4+gate
__global__ __launch_bounds__(256) void k_pack_wp(const float* __restrict__ wih,
                                                 const float* __restrict__ whh,
                                                 __half* __restrict__ wpo) {
  int mt = blockIdx.x;
  int tid = threadIdx.x;
  int ks = blockIdx.y * 4 + (tid >> 6);
  int l = tid & 63;
  int rp = mt * 16 + (l & 15);
  int u = rp >> 2, g = rp & 3;
  int row = g * 1024 + u;
  int k = ks * 32 + (l >> 4) * 8;
  const float* src = (k < 2048) ? (wih + (size_t)row * 2048 + k)
                                : (whh + (size_t)row * 1024 + (k - 2048));
  float4 a = *(const float4*)src;
  float4 b = *(const float4*)(src + 4);
  __half o[8] = {__float2half(a.x), __float2half(a.y), __float2half(a.z), __float2half(a.w),
                 __float2half(b.x), __float2half(b.y), __float2half(b.z), __float2half(b.w)};
  *(float4*)(wpo + (((size_t)mt * 96 + ks) * 64 + l) * 8) = *(float4*)o;
}

__global__ __launch_bounds__(256) void k_pack_whp(const float* __restrict__ wout,
                                                  __half* __restrict__ wpo) {
  int nt = blockIdx.x;
  int tid = threadIdx.x;
  int ks = blockIdx.y * 4 + (tid >> 6);
  int l = tid & 63;
  int row = nt * 16 + (l & 15);
  int k = ks * 32 + (l >> 4) * 8;
  const float* src = wout + (size_t)row * 2048 + 1024 + k;
  float4 a = *(const float4*)src;
  float4 b = *(const float4*)(src + 4);
  __half o[8] = {__float2half(a.x), __float2half(a.y), __float2half(a.z), __float2half(a.w),
                 __float2half(b.x), __float2half(b.y), __float2half(b.z), __float2half(b.w)};
  *(float4*)(wpo + (((size_t)nt * 32 + ks) * 64 + l) * 8) = *(float4*)o;
}

__global__ __launch_bounds__(256) void k_bias_r(const float* __restrict__ bih,
                                                const float* __restrict__ bhh,
                                                float* __restrict__ biasr) {
  int i = blockIdx.x * 256 + threadIdx.x;
  int u = i >> 2, g = i & 3;
  biasr[i] = bih[g * 1024 + u] + bhh[g * 1024 + u];
}

// MFMA precompute GEMM: [4096 x 1024] fp32 @ [1024 x 2048] f16.
// Block = 64m x 128n, 256 thr (4 waves); wave w owns m-subtile w, 8 n-subtiles.
// n0<1024 -> kpre[m][n] row-major ; else -> cwt[b][n-1024][s], m=b*128+s.
__global__ __launch_bounds__(256) void k_pregemm(const float* __restrict__ Af,
                                                 const __half* __restrict__ Bh,
                                                 __half* __restrict__ kpre,
                                                 __half* __restrict__ cwt) {
  __shared__ __half As[64 * 40];    // [m][k], stride 40 halves
  __shared__ __half Bs[128 * 40];   // [n][k] transposed, stride 40
  int tid = threadIdx.x;
  int w = tid >> 6, l = tid & 63;
  int rl = l & 15, kg = l >> 4;
  int m0 = blockIdx.x * 64;
  int n0 = blockIdx.y * 128;
  f32x4 acc[8] = {};

  int am = tid >> 2, akq = (tid & 3) * 8;       // A staging: row, k-offset
  int bkr = tid >> 4, bnc = tid & 15;           // B staging: k-row, n-octet

  for (int k0 = 0; k0 < 1024; k0 += 32) {
    const float* ap = Af + (size_t)(m0 + am) * 1024 + k0 + akq;
    float4 a0 = *(const float4*)ap;
    float4 a1 = *(const float4*)(ap + 4);
    __half o8[8] = {__float2half(a0.x), __float2half(a0.y), __float2half(a0.z), __float2half(a0.w),
                    __float2half(a1.x), __float2half(a1.y), __float2half(a1.z), __float2half(a1.w)};
    *(float4*)&As[am * 40 + akq] = *(float4*)o8;
#pragma unroll
    for (int h2 = 0; h2 < 2; ++h2) {
      int krr = bkr + h2 * 16;
      f16x8 bv = *(const f16x8*)(Bh + (size_t)(k0 + krr) * 2048 + n0 + bnc * 8);
#pragma unroll
      for (int e = 0; e < 8; ++e) Bs[(bnc * 8 + e) * 40 + krr] = (__half)(float)bv[e];
    }
    __syncthreads();
    f16x8 af = *(const f16x8*)&As[(w * 16 + rl) * 40 + kg * 8];
#pragma unroll
    for (int nn = 0; nn < 8; ++nn) {
      f16x8 bf = *(const f16x8*)&Bs[(nn * 16 + rl) * 40 + kg * 8];
      acc[nn] = __builtin_amdgcn_mfma_f32_16x16x32_f16(af, bf, acc[nn], 0, 0, 0);
    }
    __syncthreads();
  }

  if (blockIdx.y < 8) {
#pragma unroll
    for (int nn = 0; nn < 8; ++nn)
#pragma unroll
      for (int r = 0; r < 4; ++r) {
        int m = m0 + w * 16 + kg * 4 + r;
        kpre[(size_t)m * 1024 + n0 + nn * 16 + rl] = __float2half(acc[nn][r]);
      }
  } else {
    int b = m0 >> 7;
    int nlb = n0 - 1024;
#pragma unroll
    for (int nn = 0; nn < 8; ++nn)
#pragma unroll
      for (int r = 0; r < 4; ++r) {
        int s = (m0 & 127) + w * 16 + kg * 4 + r;
        int nl = nlb + nn * 16 + rl;
        cwt[((size_t)(b << 10) + nl) * 128 + s] = __float2half(acc[nn][r]);
      }
  }
}

// ---------------- split arrive/wait padded half-barrier ----------------
// Per half (128 blocks): B = bar + half*4096 (u32). Every word on its own
// 256B line:
//   part_ctr[p] = B[p*64]        p=0..7   (16 blocks each)
//   glob_ctr    = B[512]
//   part_rel[p] = B[1024+p*64]
//   poison      = B[2048]
// Last arriver (global ctr hits gen*8) writes all 8 part_rel words.

__device__ __forceinline__ void bar_arrive(unsigned* B, int hblk, unsigned gen) {
  __syncthreads();   // all block stores drained (compiler emits vmcnt before s_barrier)
  if (threadIdx.x == 0) {
    int p = hblk >> 4;
    unsigned a = __hip_atomic_fetch_add(&B[p * 64], 1u,
                                        __ATOMIC_RELAXED, __HIP_MEMORY_SCOPE_AGENT);
    if (a == gen * 16u - 1u) {
      unsigned g2 = __hip_atomic_fetch_add(&B[512], 1u,
                                           __ATOMIC_RELAXED, __HIP_MEMORY_SCOPE_AGENT);
      if (g2 == gen * 8u - 1u) {
#pragma unroll
        for (int q = 0; q < 8; ++q) astore32(&B[1024 + q * 64], gen);
      }
    }
  }
}

__device__ __forceinline__ void bar_wait(unsigned* B, int hblk, unsigned gen) {
  if (threadIdx.x == 0) {
    int p = hblk >> 4;
    unsigned spins = 0;
    while (aload32u(&B[1024 + p * 64]) < gen) {
      __builtin_amdgcn_s_sleep(1);
      if ((++spins & 255u) == 0u) {
        if (aload32u(&B[2048]) != 0u) break;
        if (spins > 2000000u) { astore32(&B[2048], 1u); break; }
      }
    }
    asm volatile("" ::: "memory");
  }
  __syncthreads();
}

// ---------------- persistent kernel ----------------
// Two independent half-grids: half = blk>>7 (batches half*16..+15), hblk=blk&127.
// Phase BC pair-split: d = hblk&1 owns local batches d*8..d*8+7; nt = hblk>>1.
// LDS map:
//  A: inp 16x6160B [0,98560) | redA [98560,104704)
//  BC: hsl 16x2064B [0,33024) (rows 0..7) | redC [33024,41216)
//      | al [41216,45440) | cx [45440,47488) | hs2 [47488,49536)
//  bar1 window: kpreL @49664 (32,768)  -> read in phase B
//  bar2 window: cwtL  @49664 (35,072)  -> read in phase C
//  bar3 window: x/h -> inp

__global__ __launch_bounds__(512, 2) void k_persist(
    const __half* __restrict__ xf, const f16x8* __restrict__ wp,
    const f16x8* __restrict__ whp, const __half* __restrict__ kpre,
    const __half* __restrict__ cwt, const float* __restrict__ biasr,
    const float* __restrict__ bout, __half* __restrict__ hbuf,
    __half* __restrict__ attn, float* __restrict__ scores,
    float* __restrict__ out, unsigned* __restrict__ bar) {
  __shared__ __align__(16) char smem[104704];
  int tid = threadIdx.x;
  int blk = blockIdx.x;
  int half = blk >> 7, hblk = blk & 127;
  unsigned* Bbar = bar + half * 4096;
  int w = tid >> 6, l = tid & 63;
  int rl = l & 15, kg = l >> 4;

  // ---- phase A roles
  int rblk = hblk, bh2 = half;
  int mh = w & 1, kq = w >> 1;
  int mtA = rblk * 2 + mh;

  f16x8 wa[24];
#pragma unroll
  for (int q = 0; q < 24; ++q)
    wa[q] = wp[((size_t)mtA * 96 + kq * 24 + q) * 64 + l];

  // ---- phase BC roles: nt = hblk>>1, pair member d owns 8 batches
  int nt = hblk >> 1, bhc = half, d = hblk & 1;
  f16x8 wc[4];
#pragma unroll
  for (int q = 0; q < 4; ++q)
    wc[q] = whp[(((size_t)nt * 32) + w * 4 + q) * 64 + l];

  float4 bvA = *(const float4*)&biasr[mtA * 16 + kg * 4];   // w<2
  float4 bo4 = *(const float4*)&bout[nt * 16 + kg * 4];     // w==0

  float creg = 0.f;

  __half* inp = (__half*)smem;
  float* redA = (float*)(smem + 98560);
  __half* hsl = (__half*)smem;
  float* redC = (float*)(smem + 33024);
  float* al   = (float*)(smem + 41216);
  float* cx   = (float*)(smem + 45440);
  __half* hs2 = (__half*)(smem + 47488);

  // phase B roles: scores for batch bbB, row srB
  int bbB = half * 16 + (hblk >> 3), s0B = (hblk & 7) * 16;
  int rloc = w * 2 + (l >> 5);            // local score row 0..15
  int srB = s0B + rloc, lkB = l & 31;

  // phase C ctx roles: n, batch-octet member, s-quarter
  int nl2 = tid & 15, bl8 = (tid >> 4) & 7, sh = tid >> 7;

  // staging roles
  int b0 = tid >> 5, c0 = tid & 31;       // phase A / kpreL: row, 32 stagers
  int bbA = bh2 * 16 + b0;
  int cb = tid >> 6, cn = (tid & 63) >> 2, cq = tid & 3;   // cwtL roles

  // pre-loop: stage x(t=0) and h=0 into inp
  {
    char* drow = (char*)inp + b0 * 6160;
    const __half* xrow = xf + ((size_t)bbA * 128 + 0) * 1024;
    float4 z = {0.f, 0.f, 0.f, 0.f};
#pragma unroll
    for (int j = 0; j < 4; ++j) {
      float4 xv = *(const float4*)(xrow + (c0 + 32 * j) * 8);
      *(float4*)(drow + (c0 + 32 * j) * 16) = xv;
      *(float4*)(drow + (256 + c0 + 32 * j) * 16) = z;
    }
  }

  for (int t = 0; t < 128; ++t) {
    int cur = t & 1;
    __half* hcur = hbuf + cur * 32768;

    // ======== phase A: attn staging + gates MFMA + cell ========
    {
      char* drow = (char*)inp + b0 * 6160;
      if (t == 0) {
        float4 z = {0.f, 0.f, 0.f, 0.f};
#pragma unroll
        for (int j = 0; j < 4; ++j)
          *(float4*)(drow + (128 + c0 + 32 * j) * 16) = z;
      } else {
        const __half* arow = attn + ((size_t)bbA << 10);
        float4 av[4];
#pragma unroll
        for (int j = 0; j < 4; ++j)
          av[j] = aload128(arow + (c0 + 32 * j) * 8);   // coherent
#pragma unroll
        for (int j = 0; j < 4; ++j)
          *(float4*)(drow + (128 + c0 + 32 * j) * 16) = av[j];
      }
      __syncthreads();
      f32x4 acc0 = {0, 0, 0, 0}, acc1 = {0, 0, 0, 0};
      const char* brow = (const char*)inp + rl * 6160 + kg * 16;
#pragma unroll
      for (int q = 0; q < 24; q += 2) {
        f16x8 bf0 = *(const f16x8*)(brow + (kq * 24 + q) * 64);
        f16x8 bf1 = *(const f16x8*)(brow + (kq * 24 + q + 1) * 64);
        acc0 = __builtin_amdgcn_mfma_f32_16x16x32_f16(wa[q], bf0, acc0, 0, 0, 0);
        acc1 = __builtin_amdgcn_mfma_f32_16x16x32_f16(wa[q + 1], bf1, acc1, 0, 0, 0);
      }
      f32x4 acc;
      acc[0] = acc0[0] + acc1[0]; acc[1] = acc0[1] + acc1[1];
      acc[2] = acc0[2] + acc1[2]; acc[3] = acc0[3] + acc1[3];
      if (kq >= 1) *(f32x4*)&redA[(((kq - 1) * 2 + mh) * 64 + l) * 4] = acc;
      __syncthreads();
      if (w < 2) {   // kq==0, mh = w
#pragma unroll
        for (int p = 0; p < 3; ++p) {
          f32x4 o = *(f32x4*)&redA[((p * 2 + mh) * 64 + l) * 4];
          acc[0] += o[0]; acc[1] += o[1]; acc[2] += o[2]; acc[3] += o[3];
        }
        float gi = acc[0] + bvA.x;
        float gf = acc[1] + bvA.y;
        float gg = acc[2] + bvA.z;
        float go = acc[3] + bvA.w;
        float si = 1.f / (1.f + __expf(-gi));
        float sf = 1.f / (1.f + __expf(-gf));
        float so = 1.f / (1.f + __expf(-go));
        creg = sf * creg + si * tanhf(gg);
        int u = rblk * 8 + mh * 4 + kg;
        int b = bh2 * 16 + rl;
        __half hv = __float2half(so * tanhf(creg));
        astore16(&hcur[((size_t)b << 10) + u], *(unsigned short*)&hv);   // coherent
      }
    }
    bar_arrive(Bbar, hblk, 3 * t + 1);
    // bar1 window: stage kpreL (16 rows x 2048B, coalesced; kpre read-only)
    {
      const __half* src = kpre + ((size_t)(bbB * 128 + s0B + b0) << 10) + c0 * 32;
      char* dst = smem + L_KPREL + b0 * 2048 + c0 * 64;
      f16x8 v0 = ((const f16x8*)src)[0];
      f16x8 v1 = ((const f16x8*)src)[1];
      f16x8 v2 = ((const f16x8*)src)[2];
      f16x8 v3 = ((const f16x8*)src)[3];
      ((f16x8*)dst)[0] = v0; ((f16x8*)dst)[1] = v1;
      ((f16x8*)dst)[2] = v2; ((f16x8*)dst)[3] = v3;
    }
    bar_wait(Bbar, hblk, 3 * t + 1);

    // ======== phase B: stage h(8 batches)+hs2 + scores (kpre from LDS) ========
    {
#pragma unroll
      for (int i2 = 0; i2 < 2; ++i2) {
        int f = i2 * 512 + tid;
        int b2 = f >> 7, u2 = f & 127;
        const __half* s = hcur + (((size_t)(bhc * 16 + d * 8 + b2)) << 10) + u2 * 8;
        char* dd = (char*)hsl + b2 * 2064 + u2 * 16;
        ((u64*)dd)[0] = aload64(s);
        ((u64*)dd)[1] = aload64(s + 4);
      }
      if (tid < 128) {
        const __half* s = hcur + ((size_t)bbB << 10) + tid * 8;
        ((u64*)&hs2[tid * 8])[0] = aload64(s);
        ((u64*)&hs2[tid * 8])[1] = aload64(s + 4);
      }
      __syncthreads();
      // scores: row srB of batch bbB, kpre row from kpreL
      {
        const char* krow = smem + L_KPREL + rloc * 2048;
        float p = 0.f;
#pragma unroll
        for (int it = 0; it < 4; ++it) {
          f16x8 kv = *(const f16x8*)(krow + it * 512 + lkB * 16);
          f16x8 hv = *(const f16x8*)&hs2[it * 256 + lkB * 8];
#pragma unroll
          for (int e = 0; e < 8; ++e) p = fmaf((float)kv[e], (float)hv[e], p);
        }
#pragma unroll
        for (int off = 16; off; off >>= 1) p += __shfl_xor(p, off);
        if (lkB == 0) astore32(&scores[bbB * 128 + srB], __float_as_uint(p));  // coherent
      }
    }
    bar_arrive(Bbar, hblk, 3 * t + 2);
    {
      // bar2 window: stage cwtL (8 b-chunks x 16 n x 128 s, coalesced 64B/thr;
      // padded strides n=272B b=4384B) ...
      {
        const __half* csrc = cwt + (((size_t)(bhc * 16 + d * 8 + cb) << 10) + nt * 16 + cn) * 128 + cq * 32;
        char* cdst = smem + L_CWTL + cb * 4384 + cn * 272 + cq * 64;
        f16x8 c0v = ((const f16x8*)csrc)[0];
        f16x8 c1v = ((const f16x8*)csrc)[1];
        f16x8 c2v = ((const f16x8*)csrc)[2];
        f16x8 c3v = ((const f16x8*)csrc)[3];
        ((f16x8*)cdst)[0] = c0v; ((f16x8*)cdst)[1] = c1v;
        ((f16x8*)cdst)[2] = c2v; ((f16x8*)cdst)[3] = c3v;
      }
      // ... overlapped with h-proj MFMA; redC persists into phase C
      f32x4 acc2 = {0, 0, 0, 0};
      const char* brow2 = (const char*)hsl + rl * 2064 + kg * 16;
#pragma unroll
      for (int q = 0; q < 4; ++q) {
        f16x8 bf = *(const f16x8*)(brow2 + (w * 4 + q) * 64);
        acc2 = __builtin_amdgcn_mfma_f32_16x16x32_f16(wc[q], bf, acc2, 0, 0, 0);
      }
      *(f32x4*)&redC[(w * 64 + l) * 4] = acc2;
    }
    bar_wait(Bbar, hblk, 3 * t + 2);

    // ======== phase C: softmax(8) + ctx (cwt from LDS) + combine + tanh ========
    {
      {
        int bl = tid >> 5, lj = tid & 31;
        if (bl < 8) {
          const float* srow = scores + (bhc * 16 + d * 8 + bl) * 128;
          float4 sv = aload128(srow + lj * 4);
          float m = fmaxf(fmaxf(sv.x, sv.y), fmaxf(sv.z, sv.w));
#pragma unroll
          for (int off = 16; off; off >>= 1) m = fmaxf(m, __shfl_xor(m, off));
          float e0 = __expf(sv.x - m), e1 = __expf(sv.y - m);
          float e2 = __expf(sv.z - m), e3 = __expf(sv.w - m);
          float s = e0 + e1 + e2 + e3;
#pragma unroll
          for (int off = 16; off; off >>= 1) s += __shfl_xor(s, off);
          float inv = 1.f / s;
          float4 av2 = {e0 * inv, e1 * inv, e2 * inv, e3 * inv};
          *(float4*)&al[bl * 132 + lj * 4] = av2;
        }
      }
      __syncthreads();
      // ctx partials: (nl2, bl8, sh) over 32 s each; cwtL LDS reads
      {
        const char* crowl = smem + L_CWTL + bl8 * 4384 + nl2 * 272 + sh * 64;
        const float* arow2 = &al[bl8 * 132 + sh * 32];
        float pc = 0.f;
#pragma unroll
        for (int s2 = 0; s2 < 4; ++s2) {
          f16x8 cv = *(const f16x8*)(crowl + s2 * 16);
#pragma unroll
          for (int e = 0; e < 8; ++e) pc = fmaf(arow2[s2 * 8 + e], (float)cv[e], pc);
        }
        cx[sh * 128 + bl8 * 16 + nl2] = pc;
      }
      __syncthreads();
      if (w == 0 && rl < 8) {
        f32x4 acc2 = {0, 0, 0, 0};
#pragma unroll
        for (int p3 = 0; p3 < 8; ++p3) {
          f32x4 o = *(f32x4*)&redC[(p3 * 64 + l) * 4];
          acc2[0] += o[0]; acc2[1] += o[1]; acc2[2] += o[2]; acc2[3] += o[3];
        }
        int bfin = bhc * 16 + d * 8 + rl;
        int n0 = nt * 16 + kg * 4;
        float vo[4];
#pragma unroll
        for (int r = 0; r < 4; ++r) {
          float cv2 = cx[0 * 128 + rl * 16 + kg * 4 + r] + cx[1 * 128 + rl * 16 + kg * 4 + r]
                    + cx[2 * 128 + rl * 16 + kg * 4 + r] + cx[3 * 128 + rl * 16 + kg * 4 + r];
          float bb2 = (r == 0) ? bo4.x : (r == 1) ? bo4.y : (r == 2) ? bo4.z : bo4.w;
          vo[r] = tanhf(acc2[r] + cv2 + bb2);
        }
        __half o4[4] = {__float2half(vo[0]), __float2half(vo[1]),
                        __float2half(vo[2]), __float2half(vo[3])};
        astore64(&attn[((size_t)bfin << 10) + n0], *(u64*)o4);   // coherent, unique writer
        float4 ov = {vo[0], vo[1], vo[2], vo[3]};
        *(float4*)&out[(((size_t)bfin * 128 + t) << 10) + n0] = ov;
      }
    }
    bar_arrive(Bbar, hblk, 3 * t + 3);
    // bar3 window: preload x_{t+1} + h_t and stage into inp LDS
    if (t < 127) {
      char* drow = (char*)inp + b0 * 6160;
      const __half* xrow = xf + ((size_t)bbA * 128 + (t + 1)) * 1024;
      const __half* hrow = hcur + ((size_t)bbA << 10);
#pragma unroll
      for (int j = 0; j < 4; ++j) {
        float4 xv = *(const float4*)(xrow + (c0 + 32 * j) * 8);
        float4 hv = aload128(hrow + (c0 + 32 * j) * 8);
        *(float4*)(drow + (c0 + 32 * j) * 16) = xv;
        *(float4*)(drow + (256 + c0 + 32 * j) * 16) = hv;
      }
    }
    bar_wait(Bbar, hblk, 3 * t + 3);
  }
}

// ---------------- launcher ----------------

extern "C" void kernel_launch(void* const* d_in, const int* in_sizes, int n_in,
                              void* d_out, int out_size, void* d_ws, size_t ws_size,
                              hipStream_t stream) {
  const float* x    = (const float*)d_in[0];
  const float* ctxp = (const float*)d_in[1];
  const float* wih  = (const float*)d_in[2];
  const float* whh  = (const float*)d_in[3];
  const float* bih  = (const float*)d_in[4];
  const float* bhh  = (const float*)d_in[5];
  const float* wq   = (const float*)d_in[6];
  const float* wout = (const float*)d_in[7];
  const float* bo   = (const float*)d_in[8];
  float* out = (float*)d_out;
  char* ws = (char*)d_ws;

  __half* xf    = (__half*)(ws + OFF_XF16);
  __half* wpq   = (__half*)(ws + OFF_WP);
  __half* whpq  = (__half*)(ws + OFF_WHP);
  __half* bcat  = (__half*)(ws + OFF_BCAT);
  __half* kpre  = (__half*)(ws + OFF_KPRE);
  __half* cwt   = (__half*)(ws + OFF_CWT);
  float*  biasr = (float*)(ws + OFF_BIASR);
  __half* hbuf  = (__half*)(ws + OFF_H2);
  __half* attn  = (__half*)(ws + OFF_ATTN);
  float*  sc    = (float*)(ws + OFF_SC);
  unsigned* bar = (unsigned*)(ws + OFF_BAR);

  hipMemsetAsync(ws + OFF_BAR, 0, 32768, stream);

  hipLaunchKernelGGL(k_cvt_x, dim3(4096), dim3(256), 0, stream, x, xf);
  hipLaunchKernelGGL(k_build_bcat, dim3(8, 1024), dim3(256), 0, stream, wq, wout, bcat);
  hipLaunchKernelGGL(k_pack_wp, dim3(256, 24), dim3(256), 0, stream, wih, whh, wpq);
  hipLaunchKernelGGL(k_pack_whp, dim3(64, 8), dim3(256), 0, stream, wout, whpq);
  hipLaunchKernelGGL(k_bias_r, dim3(16), dim3(256), 0, stream, bih, bhh, biasr);
  hipLaunchKernelGGL(k_pregemm, dim3(64, 16), dim3(256), 0, stream, ctxp, bcat, kpre, cwt);

  const f16x8* wpv = (const f16x8*)wpq;
  const f16x8* whpv = (const f16x8*)whpq;
  const __half* xfc = xf;
  const __half* kprec = kpre;
  const __half* cwtc = cwt;
  const float* biasrc = biasr;
  const float* boc = bo;
  void* args[] = {(void*)&xfc, (void*)&wpv, (void*)&whpv, (void*)&kprec, (void*)&cwtc,
                  (void*)&biasrc, (void*)&boc, (void*)&hbuf, (void*)&attn, (void*)&sc,
                  (void*)&out, (void*)&bar};
  hipLaunchCooperativeKernel((void*)k_persist, dim3(256), dim3(512), args, 0, stream);
}

// Round 14
// 1553.742 us; speedup vs baseline: 2.5691x; 1.0341x over previous
//
#include <hip/hip_runtime.h>
#include <hip/hip_fp16.h>

// B=32, T=128, Din=H=C=1024, S=128.
// R14: persistent kernel = R11 EXACTLY (best stable: 3 split arrive/wait
// flat-release barriers/step, distributed scores, phase-BC pair-split by
// batch). R13's all-observer barrier REVERTED: it raced on timed replays
// (re-validation failure) despite passing first validation — unexplained
// instability in sync = falsified (rigor.md).
// Only change vs R11: k_pregemm B-staging packs 2 k-rows per u32 LDS write
// (halves the 16 scalar ds_write_u16 per thread per K-iter; same math).
//
// MFMA 16x16x32_f16 layout (guide §3, m89-verified):
//   A: lane l, elem j -> A[l&15][(l>>4)*8+j]
//   B: lane l, elem j -> B[(l>>4)*8+j][l&15]
//   D: lane l, reg  r -> D[(l>>4)*4+r][l&15]

typedef _Float16 f16x8 __attribute__((ext_vector_type(8)));
typedef float f32x4 __attribute__((ext_vector_type(4)));
typedef unsigned long long u64;

// ---- workspace layout (bytes) ----
#define OFF_XF16  ((size_t)0)           // [32][128][1024] f16     8,388,608
#define OFF_WP    ((size_t)8388608)     // [256][96][64][8] f16   25,165,824
#define OFF_WHP   ((size_t)33554432)    // [64][32][64][8] f16     2,097,152
#define OFF_BCAT  ((size_t)35651584)    // [1024][2048] f16        4,194,304
#define OFF_KPRE  ((size_t)39845888)    // [4096][1024] f16 row-major 8,388,608
#define OFF_CWT   ((size_t)48234496)    // [32][1024][128] f16     8,388,608
#define OFF_BIASR ((size_t)56623104)    // [4096] f32                 16,384
#define OFF_H2    ((size_t)56770560)    // [2][32][1024] f16         131,072
#define OFF_ATTN  ((size_t)56901632)    // [32][1024] f16             65,536
#define OFF_SC    ((size_t)56967168)    // [32][128] f32              16,384
#define OFF_BAR   ((size_t)56983552)    // 32 KB barrier state (2 halves x 16KB)

// ---- agent-scope coherent access helpers (bypass non-coherent L2) ----
__device__ __forceinline__ u64 aload64(const void* p) {
  return __hip_atomic_load((const u64*)p, __ATOMIC_RELAXED, __HIP_MEMORY_SCOPE_AGENT);
}
__device__ __forceinline__ unsigned aload32u(const unsigned* p) {
  return __hip_atomic_load(p, __ATOMIC_RELAXED, __HIP_MEMORY_SCOPE_AGENT);
}
__device__ __forceinline__ void astore32(void* p, unsigned v) {
  __hip_atomic_store((unsigned*)p, v, __ATOMIC_RELAXED, __HIP_MEMORY_SCOPE_AGENT);
}
__device__ __forceinline__ void astore64(void* p, u64 v) {
  __hip_atomic_store((u64*)p, v, __ATOMIC_RELAXED, __HIP_MEMORY_SCOPE_AGENT);
}
__device__ __forceinline__ void astore16(void* p, unsigned short v) {
  __hip_atomic_store((unsigned short*)p, v, __ATOMIC_RELAXED, __HIP_MEMORY_SCOPE_AGENT);
}
__device__ __forceinline__ float4 aload128(const void* p) {
  float4 v;
  ((u64*)&v)[0] = aload64(p);
  ((u64*)&v)[1] = aload64((const char*)p + 8);
  return v;
}

// ---------------- one-time kernels ----------------

__global__ __launch_bounds__(256) void k_cvt_x(const float* __restrict__ x, __half* __restrict__ xf) {
  int i = blockIdx.x * 256 + threadIdx.x;
  float4 v = ((const float4*)x)[i];
  __half h4[4] = {__float2half(v.x), __float2half(v.y), __float2half(v.z), __float2half(v.w)};
  ((float2*)xf)[i] = *(float2*)h4;
}

__global__ __launch_bounds__(256) void k_build_bcat(const float* __restrict__ wq,
                                                    const float* __restrict__ wout,
                                                    __half* __restrict__ bcat) {
  int j = blockIdx.x * 256 + threadIdx.x;
  int c = blockIdx.y;
  float v = (j < 1024) ? wq[c * 1024 + j] : wout[(size_t)(j - 1024) * 2048 + c];
  bcat[c * 2048 + j] = __float2half(v);
}

// pack gate weights into MFMA A-fragment stream: wp[mt][ks][l][8]
// packed row r' = mt*16 + (l&15); original row = gate*1024 + u, r' = u*4+gate
__global__ __launch_bounds__(256) void k_pack_wp(const float* __restrict__ wih,
                                                 const float* __restrict__ whh,
                                                 __half* __restrict__ wpo) {
  int mt = blockIdx.x;
  int tid = threadIdx.x;
  int ks = blockIdx.y * 4 + (tid >> 6);
  int l = tid & 63;
  int rp = mt * 16 + (l & 15);
  int u = rp >> 2, g = rp & 3;
  int row = g * 1024 + u;
  int k = ks * 32 + (l >> 4) * 8;
  const float* src = (k < 2048) ? (wih + (size_t)row * 2048 + k)
                                : (whh + (size_t)row * 1024 + (k - 2048));
  float4 a = *(const float4*)src;
  float4 b = *(const float4*)(src + 4);
  __half o[8] = {__float2half(a.x), __float2half(a.y), __float2half(a.z), __float2half(a.w),
                 __float2half(b.x), __float2half(b.y), __float2half(b.z), __float2half(b.w)};
  *(float4*)(wpo + (((size_t)mt * 96 + ks) * 64 + l) * 8) = *(float4*)o;
}

__global__ __launch_bounds__(256) void k_pack_whp(const float* __restrict__ wout,
                                                  __half* __restrict__ wpo) {
  int nt = blockIdx.x;
  int tid = threadIdx.x;
  int ks = blockIdx.y * 4 + (tid >> 6);
  int l = tid & 63;
  int row = nt * 16 + (l & 15);
  int k = ks * 32 + (l >> 4) * 8;
  const float* src = wout + (size_t)row * 2048 + 1024 + k;
  float4 a = *(const float4*)src;
  float4 b = *(const float4*)(src + 4);
  __half o[8] = {__float2half(a.x), __float2half(a.y), __float2half(a.z), __float2half(a.w),
                 __float2half(b.x), __float2half(b.y), __float2half(b.z), __float2half(b.w)};
  *(float4*)(wpo + (((size_t)nt * 32 + ks) * 64 + l) * 8) = *(float4*)o;
}

__global__ __launch_bounds__(256) void k_bias_r(const float* __restrict__ bih,
                                                const float* __restrict__ bhh,
                                                float* __restrict__ biasr) {
  int i = blockIdx.x * 256 + threadIdx.x;
  int u = i >> 2, g = i & 3;
  biasr[i] = bih[g * 1024 + u] + bhh[g * 1024 + u];
}

// MFMA precompute GEMM: [4096 x 1024] fp32 @ [1024 x 2048] f16.
// Block = 64m x 128n, 256 thr (4 waves); wave w owns m-subtile w, 8 n-subtiles.
// n0<1024 -> kpre[m][n] row-major ; else -> cwt[b][n-1024][s], m=b*128+s.
// B-staging: each thread loads 2 adjacent k-rows (f16x8 each) and writes the
// transpose as 8 u32 (packed k-pairs) — half the LDS stores of scalar u16.
__global__ __launch_bounds__(256) void k_pregemm(const float* __restrict__ Af,
                                                 const __half* __restrict__ Bh,
                                                 __half* __restrict__ kpre,
                                                 __half* __restrict__ cwt) {
  __shared__ __half As[64 * 40];    // [m][k], stride 40 halves
  __shared__ __half Bs[128 * 40];   // [n][k] transposed, stride 40 (even)
  int tid = threadIdx.x;
  int w = tid >> 6, l = tid & 63;
  int rl = l & 15, kg = l >> 4;
  int m0 = blockIdx.x * 64;
  int n0 = blockIdx.y * 128;
  f32x4 acc[8] = {};

  int am = tid >> 2, akq = (tid & 3) * 8;       // A staging: row, k-offset
  int bkp = (tid >> 4) * 2, bnc = tid & 15;     // B staging: k-pair base, n-octet

  for (int k0 = 0; k0 < 1024; k0 += 32) {
    const float* ap = Af + (size_t)(m0 + am) * 1024 + k0 + akq;
    float4 a0 = *(const float4*)ap;
    float4 a1 = *(const float4*)(ap + 4);
    __half o8[8] = {__float2half(a0.x), __float2half(a0.y), __float2half(a0.z), __float2half(a0.w),
                    __float2half(a1.x), __float2half(a1.y), __float2half(a1.z), __float2half(a1.w)};
    *(float4*)&As[am * 40 + akq] = *(float4*)o8;
    // stage B rows k0+bkp, k0+bkp+1 transposed: 8 u32 packed writes
    {
      f16x8 v0 = *(const f16x8*)(Bh + (size_t)(k0 + bkp) * 2048 + n0 + bnc * 8);
      f16x8 v1 = *(const f16x8*)(Bh + (size_t)(k0 + bkp + 1) * 2048 + n0 + bnc * 8);
#pragma unroll
      for (int e = 0; e < 8; ++e) {
        __half pr[2] = {(__half)(float)v0[e], (__half)(float)v1[e]};
        *(unsigned*)&Bs[(bnc * 8 + e) * 40 + bkp] = *(unsigned*)pr;
      }
    }
    __syncthreads();
    f16x8 af = *(const f16x8*)&As[(w * 16 + rl) * 40 + kg * 8];
#pragma unroll
    for (int nn = 0; nn < 8; ++nn) {
      f16x8 bf = *(const f16x8*)&Bs[(nn * 16 + rl) * 40 + kg * 8];
      acc[nn] = __builtin_amdgcn_mfma_f32_16x16x32_f16(af, bf, acc[nn], 0, 0, 0);
    }
    __syncthreads();
  }

  if (blockIdx.y < 8) {
#pragma unroll
    for (int nn = 0; nn < 8; ++nn)
#pragma unroll
      for (int r = 0; r < 4; ++r) {
        int m = m0 + w * 16 + kg * 4 + r;
        kpre[(size_t)m * 1024 + n0 + nn * 16 + rl] = __float2half(acc[nn][r]);
      }
  } else {
    int b = m0 >> 7;
    int nlb = n0 - 1024;
#pragma unroll
    for (int nn = 0; nn < 8; ++nn)
#pragma unroll
      for (int r = 0; r < 4; ++r) {
        int s = (m0 & 127) + w * 16 + kg * 4 + r;
        int nl = nlb + nn * 16 + rl;
        cwt[((size_t)(b << 10) + nl) * 128 + s] = __float2half(acc[nn][r]);
      }
  }
}

// ---------------- split arrive/wait padded half-barrier (R11, proven) ----------------
// Per half (128 blocks): B = bar + half*4096 (u32). Every word on its own
// 256B line:
//   part_ctr[p] = B[p*64]        p=0..7   (16 blocks each)
//   glob_ctr    = B[512]
//   part_rel[p] = B[1024+p*64]
//   poison      = B[2048]
// Last arriver (global ctr hits gen*8) writes all 8 part_rel words.

__device__ __forceinline__ void bar_arrive(unsigned* B, int hblk, unsigned gen) {
  __syncthreads();   // all block stores drained (compiler emits vmcnt before s_barrier)
  if (threadIdx.x == 0) {
    int p = hblk >> 4;
    unsigned a = __hip_atomic_fetch_add(&B[p * 64], 1u,
                                        __ATOMIC_RELAXED, __HIP_MEMORY_SCOPE_AGENT);
    if (a == gen * 16u - 1u) {
      unsigned g2 = __hip_atomic_fetch_add(&B[512], 1u,
                                           __ATOMIC_RELAXED, __HIP_MEMORY_SCOPE_AGENT);
      if (g2 == gen * 8u - 1u) {
#pragma unroll
        for (int q = 0; q < 8; ++q) astore32(&B[1024 + q * 64], gen);
      }
    }
  }
}

__device__ __forceinline__ void bar_wait(unsigned* B, int hblk, unsigned gen) {
  if (threadIdx.x == 0) {
    int p = hblk >> 4;
    unsigned spins = 0;
    while (aload32u(&B[1024 + p * 64]) < gen) {
      __builtin_amdgcn_s_sleep(1);
      if ((++spins & 255u) == 0u) {
        if (aload32u(&B[2048]) != 0u) break;
        if (spins > 2000000u) { astore32(&B[2048], 1u); break; }
      }
    }
    asm volatile("" ::: "memory");
  }
  __syncthreads();
}

__device__ __forceinline__ void halfbar(unsigned* B, int hblk, unsigned gen) {
  bar_arrive(B, hblk, gen);
  bar_wait(B, hblk, gen);
}

// ---------------- persistent kernel (R11, verbatim) ----------------
// Two independent half-grids: half = blk>>7 (batches half*16..+15), hblk=blk&127.
// Phase BC pair-split: d = hblk&1 owns local batches d*8..d*8+7; nt = hblk>>1.
// LDS map:
//  A: inp 16x6160B [0,98560) | redA [98560,104704)
//  BC: hsl 16x2064B [0,33024) (rows 0..7 used) | redC [33024,41216)
//      | al [41216,45440) 8x132 f32 | cx [45440,47488) 512 f32
//      | hs2 [47488,49536) 2KB
//  BC->A window: x/h written into inp after bar-end arrive's syncthreads.

__global__ __launch_bounds__(512, 2) void k_persist(
    const __half* __restrict__ xf, const f16x8* __restrict__ wp,
    const f16x8* __restrict__ whp, const __half* __restrict__ kpre,
    const __half* __restrict__ cwt, const float* __restrict__ biasr,
    const float* __restrict__ bout, __half* __restrict__ hbuf,
    __half* __restrict__ attn, float* __restrict__ scores,
    float* __restrict__ out, unsigned* __restrict__ bar) {
  __shared__ __align__(16) char smem[104704];
  int tid = threadIdx.x;
  int blk = blockIdx.x;
  int half = blk >> 7, hblk = blk & 127;
  unsigned* Bbar = bar + half * 4096;
  int w = tid >> 6, l = tid & 63;
  int rl = l & 15, kg = l >> 4;

  // ---- phase A roles
  int rblk = hblk, bh2 = half;
  int mh = w & 1, kq = w >> 1;
  int mtA = rblk * 2 + mh;

  f16x8 wa[24];
#pragma unroll
  for (int q = 0; q < 24; ++q)
    wa[q] = wp[((size_t)mtA * 96 + kq * 24 + q) * 64 + l];

  // ---- phase BC roles: nt = hblk>>1, pair member d owns 8 batches
  int nt = hblk >> 1, bhc = half, d = hblk & 1;
  f16x8 wc[4];
#pragma unroll
  for (int q = 0; q < 4; ++q)
    wc[q] = whp[(((size_t)nt * 32) + w * 4 + q) * 64 + l];

  float4 bvA = *(const float4*)&biasr[mtA * 16 + kg * 4];   // w<2
  float4 bo4 = *(const float4*)&bout[nt * 16 + kg * 4];     // w==0

  float creg = 0.f;

  __half* inp = (__half*)smem;
  float* redA = (float*)(smem + 98560);
  __half* hsl = (__half*)smem;
  float* redC = (float*)(smem + 33024);
  float* al   = (float*)(smem + 41216);
  float* cx   = (float*)(smem + 45440);
  __half* hs2 = (__half*)(smem + 47488);

  // phase B roles: scores for batch bbB, row srB
  int bbB = half * 16 + (hblk >> 3), s0B = (hblk & 7) * 16;
  int srB = s0B + w * 2 + (l >> 5), lkB = l & 31;

  // phase C ctx roles: n, batch-octet member, s-quarter
  int nl2 = tid & 15, bl8 = (tid >> 4) & 7, sh = tid >> 7;

  // phase A staging roles
  int b0 = tid >> 5, c0 = tid & 31;
  int bbA = bh2 * 16 + b0;

  // pre-loop: stage x(t=0) and h=0 into inp
  {
    char* drow = (char*)inp + b0 * 6160;
    const __half* xrow = xf + ((size_t)bbA * 128 + 0) * 1024;
    float4 z = {0.f, 0.f, 0.f, 0.f};
#pragma unroll
    for (int j = 0; j < 4; ++j) {
      float4 xv = *(const float4*)(xrow + (c0 + 32 * j) * 8);
      *(float4*)(drow + (c0 + 32 * j) * 16) = xv;
      *(float4*)(drow + (256 + c0 + 32 * j) * 16) = z;
    }
  }

  for (int t = 0; t < 128; ++t) {
    int cur = t & 1;
    __half* hcur = hbuf + cur * 32768;

    // ======== phase A: attn staging + gates MFMA + cell ========
    {
      char* drow = (char*)inp + b0 * 6160;
      if (t == 0) {
        float4 z = {0.f, 0.f, 0.f, 0.f};
#pragma unroll
        for (int j = 0; j < 4; ++j)
          *(float4*)(drow + (128 + c0 + 32 * j) * 16) = z;
      } else {
        const __half* arow = attn + ((size_t)bbA << 10);
        float4 av[4];
#pragma unroll
        for (int j = 0; j < 4; ++j)
          av[j] = aload128(arow + (c0 + 32 * j) * 8);   // coherent
#pragma unroll
        for (int j = 0; j < 4; ++j)
          *(float4*)(drow + (128 + c0 + 32 * j) * 16) = av[j];
      }
      __syncthreads();
      f32x4 acc0 = {0, 0, 0, 0}, acc1 = {0, 0, 0, 0};
      const char* brow = (const char*)inp + rl * 6160 + kg * 16;
#pragma unroll
      for (int q = 0; q < 24; q += 2) {
        f16x8 bf0 = *(const f16x8*)(brow + (kq * 24 + q) * 64);
        f16x8 bf1 = *(const f16x8*)(brow + (kq * 24 + q + 1) * 64);
        acc0 = __builtin_amdgcn_mfma_f32_16x16x32_f16(wa[q], bf0, acc0, 0, 0, 0);
        acc1 = __builtin_amdgcn_mfma_f32_16x16x32_f16(wa[q + 1], bf1, acc1, 0, 0, 0);
      }
      f32x4 acc;
      acc[0] = acc0[0] + acc1[0]; acc[1] = acc0[1] + acc1[1];
      acc[2] = acc0[2] + acc1[2]; acc[3] = acc0[3] + acc1[3];
      if (kq >= 1) *(f32x4*)&redA[(((kq - 1) * 2 + mh) * 64 + l) * 4] = acc;
      __syncthreads();
      if (w < 2) {   // kq==0, mh = w
#pragma unroll
        for (int p = 0; p < 3; ++p) {
          f32x4 o = *(f32x4*)&redA[((p * 2 + mh) * 64 + l) * 4];
          acc[0] += o[0]; acc[1] += o[1]; acc[2] += o[2]; acc[3] += o[3];
        }
        float gi = acc[0] + bvA.x;
        float gf = acc[1] + bvA.y;
        float gg = acc[2] + bvA.z;
        float go = acc[3] + bvA.w;
        float si = 1.f / (1.f + __expf(-gi));
        float sf = 1.f / (1.f + __expf(-gf));
        float so = 1.f / (1.f + __expf(-go));
        creg = sf * creg + si * tanhf(gg);
        int u = rblk * 8 + mh * 4 + kg;
        int b = bh2 * 16 + rl;
        __half hv = __float2half(so * tanhf(creg));
        astore16(&hcur[((size_t)b << 10) + u], *(unsigned short*)&hv);   // coherent
      }
    }
    halfbar(Bbar, hblk, 3 * t + 1);

    // ======== phase B: stage h(8 batches)+hs2 + scores; h-proj in bar2 window ========
    {
#pragma unroll
      for (int i2 = 0; i2 < 2; ++i2) {
        int f = i2 * 512 + tid;
        int b2 = f >> 7, u2 = f & 127;
        const __half* s = hcur + (((size_t)(bhc * 16 + d * 8 + b2)) << 10) + u2 * 8;
        char* dd = (char*)hsl + b2 * 2064 + u2 * 16;
        ((u64*)dd)[0] = aload64(s);
        ((u64*)dd)[1] = aload64(s + 4);
      }
      if (tid < 128) {
        const __half* s = hcur + ((size_t)bbB << 10) + tid * 8;
        ((u64*)&hs2[tid * 8])[0] = aload64(s);
        ((u64*)&hs2[tid * 8])[1] = aload64(s + 4);
      }
      __syncthreads();
      // scores: row srB of batch bbB (kpre per-step coalesced loads)
      {
        const __half* krow = kpre + ((size_t)(bbB * 128 + srB) << 10);
        float p = 0.f;
#pragma unroll
        for (int it = 0; it < 4; ++it) {
          f16x8 kv = *(const f16x8*)(krow + it * 256 + lkB * 8);
          f16x8 hv = *(const f16x8*)&hs2[it * 256 + lkB * 8];
#pragma unroll
          for (int e = 0; e < 8; ++e) p = fmaf((float)kv[e], (float)hv[e], p);
        }
#pragma unroll
        for (int off = 16; off; off >>= 1) p += __shfl_xor(p, off);
        if (lkB == 0) astore32(&scores[bbB * 128 + srB], __float_as_uint(p));  // coherent
      }
    }
    bar_arrive(Bbar, hblk, 3 * t + 2);
    {
      // h-proj MFMA while barrier drains (B cols 0..7 valid = batches d*8..);
      // redC persists into phase C
      f32x4 acc2 = {0, 0, 0, 0};
      const char* brow2 = (const char*)hsl + rl * 2064 + kg * 16;
#pragma unroll
      for (int q = 0; q < 4; ++q) {
        f16x8 bf = *(const f16x8*)(brow2 + (w * 4 + q) * 64);
        acc2 = __builtin_amdgcn_mfma_f32_16x16x32_f16(wc[q], bf, acc2, 0, 0, 0);
      }
      *(f32x4*)&redC[(w * 64 + l) * 4] = acc2;
    }
    bar_wait(Bbar, hblk, 3 * t + 2);

    // ======== phase C: softmax(8) + ctx + combine + tanh ========
    {
      // softmax: 32 lanes per batch, 8 batches (coherent score reads)
      {
        int bl = tid >> 5, lj = tid & 31;
        if (bl < 8) {
          const float* srow = scores + (bhc * 16 + d * 8 + bl) * 128;
          float4 sv = aload128(srow + lj * 4);
          float m = fmaxf(fmaxf(sv.x, sv.y), fmaxf(sv.z, sv.w));
#pragma unroll
          for (int off = 16; off; off >>= 1) m = fmaxf(m, __shfl_xor(m, off));
          float e0 = __expf(sv.x - m), e1 = __expf(sv.y - m);
          float e2 = __expf(sv.z - m), e3 = __expf(sv.w - m);
          float s = e0 + e1 + e2 + e3;
#pragma unroll
          for (int off = 16; off; off >>= 1) s += __shfl_xor(s, off);
          float inv = 1.f / s;
          float4 av2 = {e0 * inv, e1 * inv, e2 * inv, e3 * inv};
          *(float4*)&al[bl * 132 + lj * 4] = av2;
        }
      }
      __syncthreads();
      // ctx partials: (nl2, bl8, sh) over 32 s each; cwt coalesced loads
      {
        const __half* crow = cwt + (((size_t)(bhc * 16 + d * 8 + bl8) << 10) + nt * 16 + nl2) * 128 + sh * 32;
        const float* arow2 = &al[bl8 * 132 + sh * 32];
        float pc = 0.f;
#pragma unroll
        for (int s2 = 0; s2 < 32; s2 += 8) {
          f16x8 cv = *(const f16x8*)(crow + s2);
#pragma unroll
          for (int e = 0; e < 8; ++e) pc = fmaf(arow2[s2 + e], (float)cv[e], pc);
        }
        cx[sh * 128 + bl8 * 16 + nl2] = pc;
      }
      __syncthreads();
      if (w == 0 && rl < 8) {
        f32x4 acc2 = {0, 0, 0, 0};
#pragma unroll
        for (int p3 = 0; p3 < 8; ++p3) {
          f32x4 o = *(f32x4*)&redC[(p3 * 64 + l) * 4];
          acc2[0] += o[0]; acc2[1] += o[1]; acc2[2] += o[2]; acc2[3] += o[3];
        }
        int bfin = bhc * 16 + d * 8 + rl;
        int n0 = nt * 16 + kg * 4;
        float vo[4];
#pragma unroll
        for (int r = 0; r < 4; ++r) {
          float cv2 = cx[0 * 128 + rl * 16 + kg * 4 + r] + cx[1 * 128 + rl * 16 + kg * 4 + r]
                    + cx[2 * 128 + rl * 16 + kg * 4 + r] + cx[3 * 128 + rl * 16 + kg * 4 + r];
          float bb2 = (r == 0) ? bo4.x : (r == 1) ? bo4.y : (r == 2) ? bo4.z : bo4.w;
          vo[r] = tanhf(acc2[r] + cv2 + bb2);
        }
        __half o4[4] = {__float2half(vo[0]), __float2half(vo[1]),
                        __float2half(vo[2]), __float2half(vo[3])};
        astore64(&attn[((size_t)bfin << 10) + n0], *(u64*)o4);   // coherent, unique writer
        float4 ov = {vo[0], vo[1], vo[2], vo[3]};
        *(float4*)&out[(((size_t)bfin * 128 + t) << 10) + n0] = ov;
      }
    }
    bar_arrive(Bbar, hblk, 3 * t + 3);
    // bar-end window: preload x_{t+1} + h_t and stage into inp LDS
    if (t < 127) {
      char* drow = (char*)inp + b0 * 6160;
      const __half* xrow = xf + ((size_t)bbA * 128 + (t + 1)) * 1024;
      const __half* hrow = hcur + ((size_t)bbA << 10);
#pragma unroll
      for (int j = 0; j < 4; ++j) {
        float4 xv = *(const float4*)(xrow + (c0 + 32 * j) * 8);
        float4 hv = aload128(hrow + (c0 + 32 * j) * 8);
        *(float4*)(drow + (c0 + 32 * j) * 16) = xv;
        *(float4*)(drow + (256 + c0 + 32 * j) * 16) = hv;
      }
    }
    bar_wait(Bbar, hblk, 3 * t + 3);
  }
}

// ---------------- launcher ----------------

extern "C" void kernel_launch(void* const* d_in, const int* in_sizes, int n_in,
                              void* d_out, int out_size, void* d_ws, size_t ws_size,
                              hipStream_t stream) {
  const float* x    = (const float*)d_in[0];
  const float* ctxp = (const float*)d_in[1];
  const float* wih  = (const float*)d_in[2];
  const float* whh  = (const float*)d_in[3];
  const float* bih  = (const float*)d_in[4];
  const float* bhh  = (const float*)d_in[5];
  const float* wq   = (const float*)d_in[6];
  const float* wout = (const float*)d_in[7];
  const float* bo   = (const float*)d_in[8];
  float* out = (float*)d_out;
  char* ws = (char*)d_ws;

  __half* xf    = (__half*)(ws + OFF_XF16);
  __half* wpq   = (__half*)(ws + OFF_WP);
  __half* whpq  = (__half*)(ws + OFF_WHP);
  __half* bcat  = (__half*)(ws + OFF_BCAT);
  __half* kpre  = (__half*)(ws + OFF_KPRE);
  __half* cwt   = (__half*)(ws + OFF_CWT);
  float*  biasr = (float*)(ws + OFF_BIASR);
  __half* hbuf  = (__half*)(ws + OFF_H2);
  __half* attn  = (__half*)(ws + OFF_ATTN);
  float*  sc    = (float*)(ws + OFF_SC);
  unsigned* bar = (unsigned*)(ws + OFF_BAR);

  hipMemsetAsync(ws + OFF_BAR, 0, 32768, stream);

  hipLaunchKernelGGL(k_cvt_x, dim3(4096), dim3(256), 0, stream, x, xf);
  hipLaunchKernelGGL(k_build_bcat, dim3(8, 1024), dim3(256), 0, stream, wq, wout, bcat);
  hipLaunchKernelGGL(k_pack_wp, dim3(256, 24), dim3(256), 0, stream, wih, whh, wpq);
  hipLaunchKernelGGL(k_pack_whp, dim3(64, 8), dim3(256), 0, stream, wout, whpq);
  hipLaunchKernelGGL(k_bias_r, dim3(16), dim3(256), 0, stream, bih, bhh, biasr);
  hipLaunchKernelGGL(k_pregemm, dim3(64, 16), dim3(256), 0, stream, ctxp, bcat, kpre, cwt);

  const f16x8* wpv = (const f16x8*)wpq;
  const f16x8* whpv = (const f16x8*)whpq;
  const __half* xfc = xf;
  const __half* kprec = kpre;
  const __half* cwtc = cwt;
  const float* biasrc = biasr;
  const float* boc = bo;
  void* args[] = {(void*)&xfc, (void*)&wpv, (void*)&whpv, (void*)&kprec, (void*)&cwtc,
                  (void*)&biasrc, (void*)&boc, (void*)&hbuf, (void*)&attn, (void*)&sc,
                  (void*)&out, (void*)&bar};
  hipLaunchCooperativeKernel((void*)k_persist, dim3(256), dim3(512), args, 0, stream);
}